// Round 9
// baseline (1602.826 us; speedup 1.0000x reference)
//
#include <hip/hip_runtime.h>
#include <cstdint>
#include <cstddef>

#define M_TOK   1232      // B*S
#define M_PAD   1280
#define D_MODEL 2048
#define F_FFN   8192
#define SEQ     77
#define BATCH   16
#define NHEAD   16
#define LRANK   16
#define NLAYER  2
#define ATILE   16

typedef short bf16x8 __attribute__((ext_vector_type(8)));
typedef float f32x4  __attribute__((ext_vector_type(4)));

#define AS1 __attribute__((address_space(1)))
#define AS3 __attribute__((address_space(3)))

__device__ __constant__ float NF4C[16] = {
  -1.0f, -0.6961928009986877f, -0.5250730514526367f, -0.39491748809814453f,
  -0.28444138169288635f, -0.18477343022823334f, -0.09105003625154495f, 0.0f,
  0.07958029955625534f, 0.16093020141124725f, 0.24611230194568634f,
  0.33791524171829224f, 0.44070982933044434f, 0.5626170039176941f,
  0.723855197429657f, 1.0f };

__device__ inline unsigned short f2b(float f) {
  unsigned u = __builtin_bit_cast(unsigned, f);
  u += 0x7FFFu + ((u >> 16) & 1u);   // RNE
  return (unsigned short)(u >> 16);
}
__device__ inline float b2f(unsigned short s) {
  return __builtin_bit_cast(float, ((unsigned)s) << 16);
}

// ---------------------------------------------------------------------------
// Materialize bf16 weights: W[n][k] = bf16(NF4[C[n][k]] * AM[n][k/64])
// ---------------------------------------------------------------------------
__global__ __launch_bounds__(256) void mat_w(
    const int* __restrict__ C, const float* __restrict__ AM,
    unsigned short* __restrict__ W, int K, long total8)
{
  __shared__ float tb[16];
  if (threadIdx.x < 16) tb[threadIdx.x] = NF4C[threadIdx.x];
  __syncthreads();
  const int KB = K >> 6;
  for (long i = (long)blockIdx.x * 256 + threadIdx.x; i < total8;
       i += (long)gridDim.x * 256) {
    long e = i << 3;
    int n = (int)(e / K), k = (int)(e - (long)n * K);
    float am = AM[(size_t)n * KB + (k >> 6)];
    const int4* cp = (const int4*)(C + e);
    int4 a = cp[0], b = cp[1];
    uint4 o;
    o.x = (unsigned)f2b(tb[a.x] * am) | ((unsigned)f2b(tb[a.y] * am) << 16);
    o.y = (unsigned)f2b(tb[a.z] * am) | ((unsigned)f2b(tb[a.w] * am) << 16);
    o.z = (unsigned)f2b(tb[b.x] * am) | ((unsigned)f2b(tb[b.y] * am) << 16);
    o.w = (unsigned)f2b(tb[b.z] * am) | ((unsigned)f2b(tb[b.w] * am) << 16);
    *(uint4*)(W + e) = o;
  }
}

// ---------------------------------------------------------------------------
// 8-phase 256x256 bf16 GEMM (m201-style template, plain HIP).
// 512 threads = 8 waves (2M x 4N), wave tile 128x64, BK=64, LDS 128KB dbuf.
// Per K-tile: P0{12 ds_read, mfma mi0-3 x ni0-1} P1{4, mi0-3 x ni2-3}
// P2{8, mi4-7 x ni0-1} P3{0, mi4-7 x ni2-3}; each phase stages one half-tile
// (order B0,B1,A0,A1) 6 slots ahead; vmcnt(4) at tile boundary only.
// Optional fused LoRA-2 epilogue (splitk==1).
// ---------------------------------------------------------------------------
__global__ __launch_bounds__(512) void gemm8(
    const unsigned short* __restrict__ X, const unsigned short* __restrict__ W,
    float* __restrict__ O, int mb, int N, int K, int acc_mode, int splitk,
    const float* __restrict__ T, const float* __restrict__ Bm, int sh, int nr)
{
  __shared__ __align__(16) unsigned short As[2][256 * 64];
  __shared__ __align__(16) unsigned short Bs[2][256 * 64];

  int tid = threadIdx.x;

  // XCD-chunked bijective swizzle
  int nwg = gridDim.x;
  int q8 = nwg >> 3, r8 = nwg & 7;
  int xcd = blockIdx.x & 7, pos = blockIdx.x >> 3;
  int wgid = (xcd < r8) ? (xcd * (q8 + 1) + pos)
                        : (r8 * (q8 + 1) + (xcd - r8) * q8 + pos);
  int nb = N >> 8;
  int per = mb * nb;
  int slice = wgid / per; int rem = wgid - slice * per;
  int nblk = rem / mb, mblk = rem - nblk * mb;
  int row0 = mblk << 8, col0 = nblk << 8;
  int KBtot = K >> 6, kcnt = KBtot / splitk, kbeg = slice * kcnt;

  int wave = tid >> 6, lane = tid & 63;
  int fr = lane & 15, fg = lane >> 4, s7 = fr & 7;
  int wr = wave >> 2, wc = wave & 3;         // 2M x 4N
  int xg = lane >> 3;
  int xcol = (((lane & 7) ^ (xg & 7)) << 3); // pre-swizzled source chunk

  const unsigned short* Xbase = X + (size_t)row0 * K + (size_t)kbeg * 64;
  const unsigned short* Wbase = W + (size_t)col0 * K + (size_t)kbeg * 64;

  f32x4 accm[8][4];
  #pragma unroll
  for (int i = 0; i < 8; ++i)
    #pragma unroll
    for (int j = 0; j < 4; ++j) accm[i][j] = (f32x4){0.f, 0.f, 0.f, 0.f};

  bf16x8 afr[4][2];   // current 4 mi rows x 2 k-halves
  bf16x8 bfr[4][2];   // all 4 ni x 2 k-halves (live whole tile)

  const int maxH = 4 * kcnt;
  // stage half-tile H: tile t=H>>2, sub hs=H&3 (0=Bh0,1=Bh1,2=Ah0,3=Ah1)
  auto stageH = [&](int H) {
    if (H >= maxH) return;
    int t = H >> 2, hs = H & 3;
    int buf = t & 1;
    const unsigned short* src = (hs < 2) ? Wbase : Xbase;
    unsigned short* dst = ((hs < 2) ? &Bs[buf][0] : &As[buf][0]) + (hs & 1) * 8192;
    const unsigned short* sb = src + (size_t)t * 64;
    #pragma unroll
    for (int r2 = 0; r2 < 2; ++r2) {
      int trow = (hs & 1) * 128 + r2 * 64 + wave * 8 + xg;
      const unsigned short* gp = sb + (size_t)trow * K + xcol;
      __builtin_amdgcn_global_load_lds(
          (const AS1 unsigned int*)gp,
          (AS3 unsigned int*)(dst + (r2 * 64 + wave * 8) * 64),
          16, 0, 0);
    }
  };
  auto lda = [&](int mib, int cur) {
    #pragma unroll
    for (int m2 = 0; m2 < 4; ++m2) {
      const unsigned short* xr = &As[cur][(wr * 128 + (mib + m2) * 16 + fr) * 64];
      afr[m2][0] = *(const bf16x8*)(xr + ((fg ^ s7) << 3));
      afr[m2][1] = *(const bf16x8*)(xr + (((4 | fg) ^ s7) << 3));
    }
  };
  auto ldb = [&](int nib, int cur) {
    #pragma unroll
    for (int n2 = 0; n2 < 2; ++n2) {
      const unsigned short* br = &Bs[cur][(wc * 64 + (nib + n2) * 16 + fr) * 64];
      bfr[nib + n2][0] = *(const bf16x8*)(br + ((fg ^ s7) << 3));
      bfr[nib + n2][1] = *(const bf16x8*)(br + (((4 | fg) ^ s7) << 3));
    }
  };
  auto qmfma = [&](int mib, int nib) {
    __builtin_amdgcn_s_setprio(1);
    #pragma unroll
    for (int m2 = 0; m2 < 4; ++m2)
      #pragma unroll
      for (int n2 = 0; n2 < 2; ++n2) {
        int ni = nib + n2, mi = mib + m2;
        accm[mi][ni] = __builtin_amdgcn_mfma_f32_16x16x32_bf16(
            afr[m2][0], bfr[ni][0], accm[mi][ni], 0, 0, 0);
        accm[mi][ni] = __builtin_amdgcn_mfma_f32_16x16x32_bf16(
            afr[m2][1], bfr[ni][1], accm[mi][ni], 0, 0, 0);
      }
    __builtin_amdgcn_s_setprio(0);
  };

  // ---- prologue: tile0 fully + B-halves of tile1 ----
  #pragma unroll
  for (int Hp = 0; Hp < 6; ++Hp) stageH(Hp);
  asm volatile("s_waitcnt vmcnt(4)" ::: "memory");
  __builtin_amdgcn_sched_barrier(0);
  __builtin_amdgcn_s_barrier();

  for (int t = 0; t < kcnt; ++t) {
    int cur = t & 1;
    int H0 = 4 * t;
    // ---- P0 ----
    lda(0, cur); ldb(0, cur); stageH(H0 + 6);
    __builtin_amdgcn_sched_barrier(0);
    __builtin_amdgcn_s_barrier();
    asm volatile("s_waitcnt lgkmcnt(0)" ::: "memory");
    __builtin_amdgcn_sched_barrier(0);
    qmfma(0, 0);
    __builtin_amdgcn_sched_barrier(0);
    __builtin_amdgcn_s_barrier();
    // ---- P1 ----
    ldb(2, cur); stageH(H0 + 7);
    __builtin_amdgcn_sched_barrier(0);
    __builtin_amdgcn_s_barrier();
    asm volatile("s_waitcnt lgkmcnt(0)" ::: "memory");
    __builtin_amdgcn_sched_barrier(0);
    qmfma(0, 2);
    __builtin_amdgcn_sched_barrier(0);
    __builtin_amdgcn_s_barrier();
    // ---- P2 ----
    lda(4, cur); stageH(H0 + 8);
    __builtin_amdgcn_sched_barrier(0);
    __builtin_amdgcn_s_barrier();
    asm volatile("s_waitcnt lgkmcnt(0)" ::: "memory");
    __builtin_amdgcn_sched_barrier(0);
    qmfma(4, 0);
    __builtin_amdgcn_sched_barrier(0);
    __builtin_amdgcn_s_barrier();
    // ---- P3 ----
    stageH(H0 + 9);
    __builtin_amdgcn_sched_barrier(0);
    __builtin_amdgcn_s_barrier();
    qmfma(4, 2);
    __builtin_amdgcn_sched_barrier(0);
    if (t == kcnt - 2) asm volatile("s_waitcnt vmcnt(0)" ::: "memory");
    else               asm volatile("s_waitcnt vmcnt(4)" ::: "memory");
    __builtin_amdgcn_sched_barrier(0);
    __builtin_amdgcn_s_barrier();
  }

  // ---- optional fused LoRA-2 ----
  float* Tt = (float*)&As[0][0];   // 256 x 16
  float* Bt = (float*)&Bs[0][0];   // 256 x 16
  if (T) {
    __syncthreads();
    int toff = (col0 >> sh) << 4;
    for (int idx = tid; idx < 256 * 16; idx += 512) {
      int rr = idx >> 4, c = idx & 15;
      int gm = row0 + rr;
      Tt[idx] = (gm < M_TOK) ? T[(size_t)gm * nr + toff + c] : 0.f;
      Bt[idx] = Bm[(size_t)(col0 + rr) * LRANK + c];
    }
    __syncthreads();
  }

  // ---- epilogue ----
  #pragma unroll
  for (int mi = 0; mi < 8; ++mi)
    #pragma unroll
    for (int ni = 0; ni < 4; ++ni) {
      int lm0 = wr * 128 + mi * 16 + fg * 4;
      int gnl = wc * 64 + ni * 16 + fr;
      int gn = col0 + gnl;
      #pragma unroll
      for (int r = 0; r < 4; ++r) {
        int gm = row0 + lm0 + r;
        if (gm < M_TOK) {
          size_t idx = (size_t)gm * N + gn;
          float vv = accm[mi][ni][r];
          if (T) {
            const float* tr = Tt + (lm0 + r) * 16;
            const float* br = Bt + gnl * 16;
            float s = 0.f;
            #pragma unroll
            for (int c = 0; c < 16; ++c) s += tr[c] * br[c];
            vv += 2.0f * s;
          }
          if (splitk > 1)       atomicAdd(&O[idx], vv);
          else if (acc_mode)    O[idx] += vv;
          else                  O[idx] = vv;
        }
      }
    }
}

// ---------------------------------------------------------------------------
// LoRA stage 1, 4 m-rows per block
__global__ __launch_bounds__(256) void lora1(
    const unsigned short* __restrict__ X, const float* __restrict__ A,
    float* __restrict__ T, int K)
{
  int m0 = blockIdx.x * 4, bi = blockIdx.y, nmat = gridDim.y;
  int g = threadIdx.x >> 4, l16 = threadIdx.x & 15;
  const float* ar = A + (size_t)bi * LRANK * K + (size_t)g * K;
  const unsigned short* x0 = X + (size_t)m0 * K;
  float s0 = 0.f, s1 = 0.f, s2 = 0.f, s3 = 0.f;
  for (int kk = l16 * 4; kk < K; kk += 64) {
    float4 av = *(const float4*)(ar + kk);
    ushort4 v0 = *(const ushort4*)(x0 + kk);
    ushort4 v1 = *(const ushort4*)(x0 + K + kk);
    ushort4 v2 = *(const ushort4*)(x0 + 2 * K + kk);
    ushort4 v3 = *(const ushort4*)(x0 + 3 * K + kk);
    s0 += b2f(v0.x)*av.x + b2f(v0.y)*av.y + b2f(v0.z)*av.z + b2f(v0.w)*av.w;
    s1 += b2f(v1.x)*av.x + b2f(v1.y)*av.y + b2f(v1.z)*av.z + b2f(v1.w)*av.w;
    s2 += b2f(v2.x)*av.x + b2f(v2.y)*av.y + b2f(v2.z)*av.z + b2f(v2.w)*av.w;
    s3 += b2f(v3.x)*av.x + b2f(v3.y)*av.y + b2f(v3.z)*av.z + b2f(v3.w)*av.w;
  }
  #pragma unroll
  for (int off = 8; off; off >>= 1) {
    s0 += __shfl_down(s0, off, 16);
    s1 += __shfl_down(s1, off, 16);
    s2 += __shfl_down(s2, off, 16);
    s3 += __shfl_down(s3, off, 16);
  }
  if (l16 == 0) {
    size_t base = ((size_t)m0 * nmat + bi) * LRANK + g;
    size_t rs = (size_t)nmat * LRANK;
    T[base] = s0; T[base + rs] = s1; T[base + 2*rs] = s2; T[base + 3*rs] = s3;
  }
}

// LoRA stage 2 (for split-K GEMMs), 8 m-rows per block
__global__ __launch_bounds__(256) void lora2(
    float* __restrict__ O, const float* __restrict__ T,
    const float* __restrict__ Bm, int N, int sh, int nr)
{
  int m0 = blockIdx.y * 8;
  int n = blockIdx.x * 256 + threadIdx.x;
  __shared__ float ts[8 * 48];
  for (int i = threadIdx.x; i < 8 * nr; i += 256)
    ts[(i / nr) * 48 + (i % nr)] = T[(size_t)(m0 + i / nr) * nr + (i % nr)];
  __syncthreads();
  const float4* br = (const float4*)(Bm + (size_t)n * LRANK);
  float4 b0 = br[0], b1 = br[1], b2 = br[2], b3 = br[3];
  int toff = ((n >> sh) << 4);
  #pragma unroll
  for (int mi = 0; mi < 8; ++mi) {
    const float* tsb = ts + mi * 48 + toff;
    float s = b0.x*tsb[0] + b0.y*tsb[1] + b0.z*tsb[2] + b0.w*tsb[3]
            + b1.x*tsb[4] + b1.y*tsb[5] + b1.z*tsb[6] + b1.w*tsb[7]
            + b2.x*tsb[8] + b2.y*tsb[9] + b2.z*tsb[10] + b2.w*tsb[11]
            + b3.x*tsb[12] + b3.y*tsb[13] + b3.z*tsb[14] + b3.w*tsb[15];
    O[(size_t)(m0 + mi) * N + n] += 2.0f * s;
  }
}

// ---------------------------------------------------------------------------
__global__ __launch_bounds__(256) void rmsnorm_k(
    const float* __restrict__ H, const float* __restrict__ W,
    unsigned short* __restrict__ X, int D)
{
  int m = blockIdx.x;
  const float* hr = H + (size_t)m * D;
  float s = 0.f;
  for (int i = threadIdx.x; i < D; i += 256) { float v = hr[i]; s += v * v; }
  __shared__ float red[4];
  #pragma unroll
  for (int off = 32; off; off >>= 1) s += __shfl_down(s, off, 64);
  if ((threadIdx.x & 63) == 0) red[threadIdx.x >> 6] = s;
  __syncthreads();
  float tot = red[0] + red[1] + red[2] + red[3];
  float inv = rsqrtf(tot / (float)D + 1e-6f);
  for (int i = threadIdx.x; i < D; i += 256)
    X[(size_t)m * D + i] = f2b(hr[i] * inv * W[i]);
}

__global__ void rope_table(float* __restrict__ cosT, float* __restrict__ sinT)
{
  int idx = blockIdx.x * 64 + threadIdx.x;
  if (idx >= SEQ * 64) return;
  int s = idx >> 6, j = idx & 63;
  float inv = powf(10000.0f, -(float)(2 * j) / 128.0f);
  float f = (float)s * inv;
  cosT[idx] = cosf(f);
  sinT[idx] = sinf(f);
}

// QKV packed buffer: row stride 6144; q at +0, k at +2048
__global__ void rope_apply(float* __restrict__ QKV,
                           const float* __restrict__ cosT, const float* __restrict__ sinT)
{
  size_t idx = (size_t)blockIdx.x * 256 + threadIdx.x;
  if (idx >= (size_t)M_TOK * NHEAD * 64) return;
  int j = (int)(idx & 63);
  int h = (int)((idx >> 6) & (NHEAD - 1));
  int m = (int)(idx >> 10);
  int s = m % SEQ;
  float c = cosT[s * 64 + j], sn = sinT[s * 64 + j];
  size_t base = (size_t)m * (3 * D_MODEL) + h * 128;
  float q1 = QKV[base + j], q2 = QKV[base + 64 + j];
  QKV[base + j]      = q1 * c - q2 * sn;
  QKV[base + 64 + j] = q2 * c + q1 * sn;
  size_t kb = base + D_MODEL;
  float k1 = QKV[kb + j], k2 = QKV[kb + 64 + j];
  QKV[kb + j]      = k1 * c - k2 * sn;
  QKV[kb + 64 + j] = k2 * c + k1 * sn;
}

// ---------------------------------------------------------------------------
__global__ __launch_bounds__(256) void attn_k(
    const float* __restrict__ QKV, const int* __restrict__ amask,
    unsigned short* __restrict__ O)
{
  int bh = blockIdx.x, it = blockIdx.y;
  int b = bh >> 4, h = bh & (NHEAD - 1);
  const int STR = 3 * D_MODEL;
  __shared__ float ks[SEQ * 132];
  __shared__ float sc[ATILE * 80];
  __shared__ int am[SEQ];
  const float scale = 0.08838834764831845f;  // 1/sqrt(128)

  const float* Kbase = QKV + (size_t)(b * SEQ) * STR + D_MODEL + h * 128;
  for (int idx = threadIdx.x; idx < SEQ * 32; idx += 256) {
    int j = idx >> 5, d4 = (idx & 31) << 2;
    *(float4*)(ks + j * 132 + d4) = *(const float4*)(Kbase + (size_t)j * STR + d4);
  }
  for (int j = threadIdx.x; j < SEQ; j += 256) am[j] = amask[b * SEQ + j];
  __syncthreads();

  int wave = threadIdx.x >> 6, lane = threadIdx.x & 63;
  #pragma unroll
  for (int r = 0; r < 4; ++r) {
    int il = wave * 4 + r;
    int i = it * ATILE + il;
    if (i < SEQ) {
      const float4* qr = (const float4*)(QKV + (size_t)(b * SEQ + i) * STR + h * 128);
      int j1 = lane, j2 = lane + 64;
      float v1 = -1e9f, v2 = -1e9f;
      if (j1 <= i && am[j1]) {
        const float4* kr = (const float4*)(ks + j1 * 132);
        float s = 0.f;
        #pragma unroll 8
        for (int d = 0; d < 32; ++d) {
          float4 a = qr[d], c = kr[d];
          s += a.x*c.x + a.y*c.y + a.z*c.z + a.w*c.w;
        }
        v1 = s * scale;
      }
      if (j2 < SEQ && j2 <= i && am[j2]) {
        const float4* kr = (const float4*)(ks + j2 * 132);
        float s = 0.f;
        #pragma unroll 8
        for (int d = 0; d < 32; ++d) {
          float4 a = qr[d], c = kr[d];
          s += a.x*c.x + a.y*c.y + a.z*c.z + a.w*c.w;
        }
        v2 = s * scale;
      }
      float mx = fmaxf(v1, v2);
      #pragma unroll
      for (int off = 32; off; off >>= 1) mx = fmaxf(mx, __shfl_xor(mx, off));
      float e1 = __expf(v1 - mx);
      float e2 = (j2 < SEQ) ? __expf(v2 - mx) : 0.f;
      float sum = e1 + e2;
      #pragma unroll
      for (int off = 32; off; off >>= 1) sum += __shfl_xor(sum, off);
      float inv = 1.0f / sum;
      sc[il * 80 + j1] = e1 * inv;
      if (j2 < SEQ) sc[il * 80 + j2] = e2 * inv;
    }
  }
  __syncthreads();

  const float* Vbase = QKV + (size_t)(b * SEQ) * STR + 2 * D_MODEL + h * 128;
  for (int idx = threadIdx.x; idx < ATILE * 32; idx += 256) {
    int il = idx >> 5, d4 = (idx & 31) << 2;
    int i = it * ATILE + il;
    if (i >= SEQ) continue;
    float4 acc = {0.f, 0.f, 0.f, 0.f};
    const float* sr = sc + il * 80;
    for (int j = 0; j < SEQ; ++j) {
      float pp = sr[j];
      float4 v = *(const float4*)(Vbase + (size_t)j * STR + d4);
      acc.x += pp * v.x; acc.y += pp * v.y; acc.z += pp * v.z; acc.w += pp * v.w;
    }
    unsigned short* op = O + (size_t)(b * SEQ + i) * D_MODEL + h * 128 + d4;
    op[0] = f2b(acc.x); op[1] = f2b(acc.y); op[2] = f2b(acc.z); op[3] = f2b(acc.w);
  }
}

__global__ void embed_gather(const float* __restrict__ E, const int* __restrict__ ids,
                             float* __restrict__ H)
{
  size_t idx = (size_t)blockIdx.x * 256 + threadIdx.x;
  int m = (int)(idx / D_MODEL);
  int n = (int)(idx % D_MODEL);
  H[idx] = E[(size_t)ids[m] * D_MODEL + n];
}

// GU packed buffer: row stride 16384; g at +0, up at +8192. Output bf16.
__global__ void silu_mul(const float* __restrict__ GU, unsigned short* __restrict__ GB)
{
  size_t id = (size_t)blockIdx.x * 256 + threadIdx.x;
  int m = (int)(id >> 13), n = (int)(id & (F_FFN - 1));
  float g = GU[(size_t)m * 2 * F_FFN + n];
  float u = GU[(size_t)m * 2 * F_FFN + F_FFN + n];
  float sig = 1.0f / (1.0f + expf(-g));
  GB[id] = f2b(g * sig * u);
}

__global__ __launch_bounds__(256) void final_k(
    const float* __restrict__ H, const int* __restrict__ amask,
    const float* __restrict__ W, float* __restrict__ out)
{
  int b = blockIdx.x;
  __shared__ int len;
  if (threadIdx.x == 0) {
    int s = 0;
    for (int j = 0; j < SEQ; ++j) s += amask[b * SEQ + j];
    len = s - 1;
  }
  __syncthreads();
  const float* hr = H + ((size_t)(b * SEQ + len) * D_MODEL);
  float s = 0.f;
  for (int i = threadIdx.x; i < D_MODEL; i += 256) { float v = hr[i]; s += v * v; }
  __shared__ float red[4];
  #pragma unroll
  for (int off = 32; off; off >>= 1) s += __shfl_down(s, off, 64);
  if ((threadIdx.x & 63) == 0) red[threadIdx.x >> 6] = s;
  __syncthreads();
  float tot = red[0] + red[1] + red[2] + red[3];
  float inv = rsqrtf(tot / (float)D_MODEL + 1e-6f);
  for (int i = threadIdx.x; i < D_MODEL; i += 256)
    out[(size_t)b * D_MODEL + i] = hr[i] * inv * W[i];
}

// ---------------------------------------------------------------------------
extern "C" void kernel_launch(void* const* d_in, const int* in_sizes, int n_in,
                              void* d_out, int out_size, void* d_ws, size_t ws_size,
                              hipStream_t stream) {
  const int*   ids     = (const int*)d_in[0];
  const int*   amask   = (const int*)d_in[1];
  const float* embed   = (const float*)d_in[2];
  const float* ln_attn = (const float*)d_in[3];
  const float* ln_mlp  = (const float*)d_in[4];
  const float* ln_fin  = (const float*)d_in[5];
  const int*   qkvC    = (const int*)d_in[6];
  const float* qkvS    = (const float*)d_in[7];
  const float* qkvA    = (const float*)d_in[8];
  const float* qkvB    = (const float*)d_in[9];
  const int*   oC      = (const int*)d_in[10];
  const float* oS      = (const float*)d_in[11];
  const float* oA      = (const float*)d_in[12];
  const float* oB      = (const float*)d_in[13];
  const int*   guC     = (const int*)d_in[14];
  const float* guS     = (const float*)d_in[15];
  const float* guA     = (const float*)d_in[16];
  const float* guB     = (const float*)d_in[17];
  const int*   dnC     = (const int*)d_in[18];
  const float* dnS     = (const float*)d_in[19];
  const float* dnA     = (const float*)d_in[20];
  const float* dnB     = (const float*)d_in[21];
  float* out = (float*)d_out;

  const int M = M_TOK, Mp = M_PAD, D = D_MODEL, F = F_FFN, R = LRANK;
  float* p = (float*)d_ws;
  float* h    = p; p += (size_t)Mp * D;
  float* qkv  = p; p += (size_t)Mp * 3 * D;   // also reused as gbf (bf16) later
  float* gu   = p; p += (size_t)Mp * 2 * F;
  float* t    = p; p += (size_t)Mp * 48;
  float* cosT = p; p += SEQ * 64;
  float* sinT = p; p += SEQ * 64;
  unsigned short* xbf = (unsigned short*)p; p += (size_t)Mp * D / 2;
  unsigned short* gbf = (unsigned short*)qkv;   // Mp*F ushorts <= Mp*3*D floats
  unsigned short* wbuf = (unsigned short*)p;    // bf16 weight buffer
  p += (size_t)2 * F * D / 2;

  rope_table<<<(SEQ*64 + 63)/64, 64, 0, stream>>>(cosT, sinT);
  embed_gather<<<(M * D)/256, 256, 0, stream>>>(embed, ids, h);

  const int mb = Mp / 256;   // 5

  for (int l = 0; l < NLAYER; ++l) {
    // ---- attention ----
    rmsnorm_k<<<M, 256, 0, stream>>>(h, ln_attn + (size_t)l * D, xbf, D);
    lora1<<<dim3(M/4, 3), 256, 0, stream>>>(xbf, qkvA + (size_t)l*3*R*D, t, D);
    mat_w<<<4096, 256, 0, stream>>>(qkvC + (size_t)l*3*D*D, qkvS + (size_t)l*3*D*(D/64),
                                    wbuf, D, (long)3*D*D/8);
    gemm8<<<mb * (3*D/256), 512, 0, stream>>>(
        xbf, wbuf, qkv, mb, 3*D, D, 0, 1,
        t, qkvB + (size_t)l*3*D*R, 11, 48);
    rope_apply<<<((size_t)M*NHEAD*64 + 255)/256, 256, 0, stream>>>(qkv, cosT, sinT);
    attn_k<<<dim3(BATCH*NHEAD, (SEQ + ATILE - 1)/ATILE), 256, 0, stream>>>(qkv, amask, xbf);
    mat_w<<<2048, 256, 0, stream>>>(oC + (size_t)l*D*D, oS + (size_t)l*D*(D/64),
                                    wbuf, D, (long)D*D/8);
    gemm8<<<mb * (D/256) * 8, 512, 0, stream>>>(
        xbf, wbuf, h, mb, D, D, 1, 8, nullptr, nullptr, 0, 0);
    lora1<<<dim3(M/4, 1), 256, 0, stream>>>(xbf, oA + (size_t)l*R*D, t, D);
    lora2<<<dim3(D/256, M/8), 256, 0, stream>>>(h, t, oB + (size_t)l*D*R, D, 11, 16);

    // ---- MLP ----
    rmsnorm_k<<<M, 256, 0, stream>>>(h, ln_mlp + (size_t)l * D, xbf, D);
    lora1<<<dim3(M/4, 2), 256, 0, stream>>>(xbf, guA + (size_t)l*2*R*D, t, D);
    mat_w<<<4096, 256, 0, stream>>>(guC + (size_t)l*2*F*D, guS + (size_t)l*2*F*(D/64),
                                    wbuf, D, (long)2*F*D/8);
    gemm8<<<mb * (2*F/256), 512, 0, stream>>>(
        xbf, wbuf, gu, mb, 2*F, D, 0, 1,
        t, guB + (size_t)l*2*F*R, 13, 32);
    silu_mul<<<((size_t)M * F)/256, 256, 0, stream>>>(gu, gbf);
    mat_w<<<4096, 256, 0, stream>>>(dnC + (size_t)l*D*F, dnS + (size_t)l*D*(F/64),
                                    wbuf, F, (long)D*F/8);
    gemm8<<<mb * (D/256) * 8, 512, 0, stream>>>(
        gbf, wbuf, h, mb, D, F, 1, 8, nullptr, nullptr, 0, 0);
    lora1<<<dim3(M/4, 1), 256, 0, stream>>>(gbf, dnA + (size_t)l*R*F, t, F);
    lora2<<<dim3(D/256, M/8), 256, 0, stream>>>(h, t, dnB + (size_t)l*D*R, D, 11, 16);
  }
  final_k<<<BATCH, 256, 0, stream>>>(h, amask, ln_fin, out);
}

// Round 10
// 1335.861 us; speedup vs baseline: 1.1998x; 1.1998x over previous
//
#include <hip/hip_runtime.h>
#include <cstdint>
#include <cstddef>

#define M_TOK   1232      // B*S
#define M_PAD   1280
#define D_MODEL 2048
#define F_FFN   8192
#define SEQ     77
#define BATCH   16
#define NHEAD   16
#define LRANK   16
#define NLAYER  2
#define ATILE   16

typedef short bf16x8 __attribute__((ext_vector_type(8)));
typedef float f32x4  __attribute__((ext_vector_type(4)));

__device__ __constant__ float NF4C[16] = {
  -1.0f, -0.6961928009986877f, -0.5250730514526367f, -0.39491748809814453f,
  -0.28444138169288635f, -0.18477343022823334f, -0.09105003625154495f, 0.0f,
  0.07958029955625534f, 0.16093020141124725f, 0.24611230194568634f,
  0.33791524171829224f, 0.44070982933044434f, 0.5626170039176941f,
  0.723855197429657f, 1.0f };

__device__ inline unsigned short f2b(float f) {
  unsigned u = __builtin_bit_cast(unsigned, f);
  u += 0x7FFFu + ((u >> 16) & 1u);   // RNE
  return (unsigned short)(u >> 16);
}
__device__ inline float b2f(unsigned short s) {
  return __builtin_bit_cast(float, ((unsigned)s) << 16);
}

// ---------------------------------------------------------------------------
// Materialize bf16 weights: W[n][k] = bf16(NF4[C[n][k]] * AM[n][k/64])
// ---------------------------------------------------------------------------
__global__ __launch_bounds__(256) void mat_w(
    const int* __restrict__ C, const float* __restrict__ AM,
    unsigned short* __restrict__ W, int K, long total8)
{
  __shared__ float tb[16];
  if (threadIdx.x < 16) tb[threadIdx.x] = NF4C[threadIdx.x];
  __syncthreads();
  const int KB = K >> 6;
  for (long i = (long)blockIdx.x * 256 + threadIdx.x; i < total8;
       i += (long)gridDim.x * 256) {
    long e = i << 3;                    // element index (multiple of 8)
    int n = (int)(e / K), k = (int)(e - (long)n * K);
    float am = AM[(size_t)n * KB + (k >> 6)];
    const int4* cp = (const int4*)(C + e);
    int4 a = cp[0], b = cp[1];
    uint4 o;
    o.x = (unsigned)f2b(tb[a.x] * am) | ((unsigned)f2b(tb[a.y] * am) << 16);
    o.y = (unsigned)f2b(tb[a.z] * am) | ((unsigned)f2b(tb[a.w] * am) << 16);
    o.z = (unsigned)f2b(tb[b.x] * am) | ((unsigned)f2b(tb[b.y] * am) << 16);
    o.w = (unsigned)f2b(tb[b.z] * am) | ((unsigned)f2b(tb[b.w] * am) << 16);
    *(uint4*)(W + e) = o;
  }
}

// ---------------------------------------------------------------------------
// bf16 GEMM, m97 structure: single-buffered 32KB LDS -> 5 blocks/CU
// (cross-block wave rotation hides the barrier vmcnt drain, m114), two
// barriers per K-tile, global_load_lds staging with pre-swizzled source.
// (256,2): VGPR ~88 — do NOT raise min-waves (R7: VGPR 64 serialized MFMA).
// Optional fused LoRA-2 epilogue (splitk==1 only).
// ---------------------------------------------------------------------------
__global__ __launch_bounds__(256, 2) void gemm_bf(
    const unsigned short* __restrict__ X, const unsigned short* __restrict__ W,
    float* __restrict__ O, int mb, int N, int K, int acc_mode, int splitk,
    const float* __restrict__ T, const float* __restrict__ Bm, int sh, int nr)
{
  __shared__ __align__(16) unsigned short xs[128 * 64];
  __shared__ __align__(16) unsigned short ws[128 * 64];

  int tid = threadIdx.x;

  // XCD-chunked bijective swizzle
  int nwg = gridDim.x;
  int q8 = nwg >> 3, r8 = nwg & 7;
  int xcd = blockIdx.x & 7, pos = blockIdx.x >> 3;
  int wgid = (xcd < r8) ? (xcd * (q8 + 1) + pos)
                        : (r8 * (q8 + 1) + (xcd - r8) * q8 + pos);
  int nb = N >> 7;
  int per = mb * nb;
  int slice = wgid / per; int rem = wgid - slice * per;
  int nblk = rem / mb, mblk = rem - nblk * mb;
  int row0 = mblk << 7, col0 = nblk << 7;
  int KBtot = K >> 6, kcnt = KBtot / splitk, kbeg = slice * kcnt;

  int wave = tid >> 6, lane = tid & 63;
  int fr = lane & 15, fg = lane >> 4, s7 = fr & 7;
  int wm = (wave >> 1) * 64, wn = (wave & 1) * 64;
  int xg = lane >> 3;
  int xcol = (((lane & 7) ^ (xg & 7)) << 3);

  const unsigned short* Xbase = X + (size_t)row0 * K + (size_t)kbeg * 64;
  const unsigned short* Wbase = W + (size_t)col0 * K + (size_t)kbeg * 64;

  f32x4 accm[4][4];
  #pragma unroll
  for (int i = 0; i < 4; ++i)
    #pragma unroll
    for (int j = 0; j < 4; ++j) accm[i][j] = (f32x4){0.f, 0.f, 0.f, 0.f};

  auto stage = [&](int t) {
    const unsigned short* xb = Xbase + (size_t)t * 64;
    const unsigned short* wb = Wbase + (size_t)t * 64;
    #pragma unroll
    for (int p2 = 0; p2 < 4; ++p2) {
      int c = wave * 4 + p2;
      const unsigned short* gp = xb + (size_t)(c * 8 + xg) * K + xcol;
      __builtin_amdgcn_global_load_lds(
          (const __attribute__((address_space(1))) unsigned int*)gp,
          (__attribute__((address_space(3))) unsigned int*)(xs + c * 512),
          16, 0, 0);
    }
    #pragma unroll
    for (int p2 = 0; p2 < 4; ++p2) {
      int c = wave * 4 + p2;
      const unsigned short* gp = wb + (size_t)(c * 8 + xg) * K + xcol;
      __builtin_amdgcn_global_load_lds(
          (const __attribute__((address_space(1))) unsigned int*)gp,
          (__attribute__((address_space(3))) unsigned int*)(ws + c * 512),
          16, 0, 0);
    }
  };
  auto compute = [&]() {
    bf16x8 b0[4], b1[4];
    #pragma unroll
    for (int ni = 0; ni < 4; ++ni) {
      const unsigned short* wr = ws + (wn + ni * 16 + fr) * 64;
      b0[ni] = *(const bf16x8*)(wr + ((fg ^ s7) << 3));
      b1[ni] = *(const bf16x8*)(wr + (((4 | fg) ^ s7) << 3));
    }
    #pragma unroll
    for (int mi = 0; mi < 4; ++mi) {
      const unsigned short* xr = xs + (wm + mi * 16 + fr) * 64;
      bf16x8 a0 = *(const bf16x8*)(xr + ((fg ^ s7) << 3));
      bf16x8 a1 = *(const bf16x8*)(xr + (((4 | fg) ^ s7) << 3));
      #pragma unroll
      for (int ni = 0; ni < 4; ++ni) {
        accm[mi][ni] = __builtin_amdgcn_mfma_f32_16x16x32_bf16(
            a0, b0[ni], accm[mi][ni], 0, 0, 0);
        accm[mi][ni] = __builtin_amdgcn_mfma_f32_16x16x32_bf16(
            a1, b1[ni], accm[mi][ni], 0, 0, 0);
      }
    }
  };

  stage(0);
  for (int t = 0; t < kcnt; ++t) {
    __syncthreads();                 // staged tile t complete & visible
    compute();
    if (t + 1 < kcnt) {
      __syncthreads();               // all waves done reading LDS
      stage(t + 1);
    }
  }

  // optional fused LoRA-2: stage T[128][16], Bm[128][16] into (free) LDS
  float* Tt = (float*)&xs[0];
  float* Bt = (float*)&ws[0];
  if (T) {
    __syncthreads();                 // done reading xs/ws from last compute
    int toff = (col0 >> sh) << 4;
    for (int idx = tid; idx < 128 * 16; idx += 256) {
      int rr = idx >> 4, c = idx & 15;
      int gm = row0 + rr;
      Tt[idx] = (gm < M_TOK) ? T[(size_t)gm * nr + toff + c] : 0.f;
      Bt[idx] = Bm[(size_t)(col0 + rr) * LRANK + c];
    }
    __syncthreads();
  }

  // epilogue
  #pragma unroll
  for (int mi = 0; mi < 4; ++mi)
    #pragma unroll
    for (int ni = 0; ni < 4; ++ni) {
      int gm0 = row0 + wm + mi * 16 + fg * 4;
      int gnl = wn + ni * 16 + fr;
      int gn = col0 + gnl;
      #pragma unroll
      for (int r = 0; r < 4; ++r) {
        int gm = gm0 + r;
        if (gm < M_TOK) {
          size_t idx = (size_t)gm * N + gn;
          float vv = accm[mi][ni][r];
          if (T) {
            const float* tr = Tt + (wm + mi * 16 + fg * 4 + r) * 16;
            const float* br = Bt + gnl * 16;
            float s = 0.f;
            #pragma unroll
            for (int c = 0; c < 16; ++c) s += tr[c] * br[c];
            vv += 2.0f * s;
          }
          if (splitk > 1)       atomicAdd(&O[idx], vv);
          else if (acc_mode)    O[idx] += vv;
          else                  O[idx] = vv;
        }
      }
    }
}

// ---------------------------------------------------------------------------
// LoRA stage 1, 4 m-rows per block: T[m][bi*16+g] = sum_k X[m][k]*A[bi][g][k]
__global__ __launch_bounds__(256) void lora1(
    const unsigned short* __restrict__ X, const float* __restrict__ A,
    float* __restrict__ T, int K)
{
  int m0 = blockIdx.x * 4, bi = blockIdx.y, nmat = gridDim.y;
  int g = threadIdx.x >> 4, l16 = threadIdx.x & 15;
  const float* ar = A + (size_t)bi * LRANK * K + (size_t)g * K;
  const unsigned short* x0 = X + (size_t)m0 * K;
  float s0 = 0.f, s1 = 0.f, s2 = 0.f, s3 = 0.f;
  for (int kk = l16 * 4; kk < K; kk += 64) {
    float4 av = *(const float4*)(ar + kk);
    ushort4 v0 = *(const ushort4*)(x0 + kk);
    ushort4 v1 = *(const ushort4*)(x0 + K + kk);
    ushort4 v2 = *(const ushort4*)(x0 + 2 * K + kk);
    ushort4 v3 = *(const ushort4*)(x0 + 3 * K + kk);
    s0 += b2f(v0.x)*av.x + b2f(v0.y)*av.y + b2f(v0.z)*av.z + b2f(v0.w)*av.w;
    s1 += b2f(v1.x)*av.x + b2f(v1.y)*av.y + b2f(v1.z)*av.z + b2f(v1.w)*av.w;
    s2 += b2f(v2.x)*av.x + b2f(v2.y)*av.y + b2f(v2.z)*av.z + b2f(v2.w)*av.w;
    s3 += b2f(v3.x)*av.x + b2f(v3.y)*av.y + b2f(v3.z)*av.z + b2f(v3.w)*av.w;
  }
  #pragma unroll
  for (int off = 8; off; off >>= 1) {
    s0 += __shfl_down(s0, off, 16);
    s1 += __shfl_down(s1, off, 16);
    s2 += __shfl_down(s2, off, 16);
    s3 += __shfl_down(s3, off, 16);
  }
  if (l16 == 0) {
    size_t base = ((size_t)m0 * nmat + bi) * LRANK + g;
    size_t rs = (size_t)nmat * LRANK;
    T[base] = s0; T[base + rs] = s1; T[base + 2*rs] = s2; T[base + 3*rs] = s3;
  }
}

// LoRA stage 2 (separate path for split-K GEMMs), 8 m-rows per block
__global__ __launch_bounds__(256) void lora2(
    float* __restrict__ O, const float* __restrict__ T,
    const float* __restrict__ Bm, int N, int sh, int nr)
{
  int m0 = blockIdx.y * 8;
  int n = blockIdx.x * 256 + threadIdx.x;
  __shared__ float ts[8 * 48];
  for (int i = threadIdx.x; i < 8 * nr; i += 256)
    ts[(i / nr) * 48 + (i % nr)] = T[(size_t)(m0 + i / nr) * nr + (i % nr)];
  __syncthreads();
  const float4* br = (const float4*)(Bm + (size_t)n * LRANK);
  float4 b0 = br[0], b1 = br[1], b2 = br[2], b3 = br[3];
  int toff = ((n >> sh) << 4);
  #pragma unroll
  for (int mi = 0; mi < 8; ++mi) {
    const float* tsb = ts + mi * 48 + toff;
    float s = b0.x*tsb[0] + b0.y*tsb[1] + b0.z*tsb[2] + b0.w*tsb[3]
            + b1.x*tsb[4] + b1.y*tsb[5] + b1.z*tsb[6] + b1.w*tsb[7]
            + b2.x*tsb[8] + b2.y*tsb[9] + b2.z*tsb[10] + b2.w*tsb[11]
            + b3.x*tsb[12] + b3.y*tsb[13] + b3.z*tsb[14] + b3.w*tsb[15];
    O[(size_t)(m0 + mi) * N + n] += 2.0f * s;
  }
}

// ---------------------------------------------------------------------------
__global__ __launch_bounds__(256) void rmsnorm_k(
    const float* __restrict__ H, const float* __restrict__ W,
    unsigned short* __restrict__ X, int D)
{
  int m = blockIdx.x;
  const float* hr = H + (size_t)m * D;
  float s = 0.f;
  for (int i = threadIdx.x; i < D; i += 256) { float v = hr[i]; s += v * v; }
  __shared__ float red[4];
  #pragma unroll
  for (int off = 32; off; off >>= 1) s += __shfl_down(s, off, 64);
  if ((threadIdx.x & 63) == 0) red[threadIdx.x >> 6] = s;
  __syncthreads();
  float tot = red[0] + red[1] + red[2] + red[3];
  float inv = rsqrtf(tot / (float)D + 1e-6f);
  for (int i = threadIdx.x; i < D; i += 256)
    X[(size_t)m * D + i] = f2b(hr[i] * inv * W[i]);
}

__global__ void rope_table(float* __restrict__ cosT, float* __restrict__ sinT)
{
  int idx = blockIdx.x * 64 + threadIdx.x;
  if (idx >= SEQ * 64) return;
  int s = idx >> 6, j = idx & 63;
  float inv = powf(10000.0f, -(float)(2 * j) / 128.0f);
  float f = (float)s * inv;
  cosT[idx] = cosf(f);
  sinT[idx] = sinf(f);
}

// QKV packed buffer: row stride 6144; q at +0, k at +2048
__global__ void rope_apply(float* __restrict__ QKV,
                           const float* __restrict__ cosT, const float* __restrict__ sinT)
{
  size_t idx = (size_t)blockIdx.x * 256 + threadIdx.x;
  if (idx >= (size_t)M_TOK * NHEAD * 64) return;
  int j = (int)(idx & 63);
  int h = (int)((idx >> 6) & (NHEAD - 1));
  int m = (int)(idx >> 10);
  int s = m % SEQ;
  float c = cosT[s * 64 + j], sn = sinT[s * 64 + j];
  size_t base = (size_t)m * (3 * D_MODEL) + h * 128;
  float q1 = QKV[base + j], q2 = QKV[base + 64 + j];
  QKV[base + j]      = q1 * c - q2 * sn;
  QKV[base + 64 + j] = q2 * c + q1 * sn;
  size_t kb = base + D_MODEL;
  float k1 = QKV[kb + j], k2 = QKV[kb + 64 + j];
  QKV[kb + j]      = k1 * c - k2 * sn;
  QKV[kb + 64 + j] = k2 * c + k1 * sn;
}

// ---------------------------------------------------------------------------
// Attention: grid (B*H, 5 row-tiles of 16). K staged in LDS (pad 132),
// wave-parallel softmax, coalesced PV from L2.
// ---------------------------------------------------------------------------
__global__ __launch_bounds__(256) void attn_k(
    const float* __restrict__ QKV, const int* __restrict__ amask,
    unsigned short* __restrict__ O)
{
  int bh = blockIdx.x, it = blockIdx.y;
  int b = bh >> 4, h = bh & (NHEAD - 1);
  const int STR = 3 * D_MODEL;
  __shared__ float ks[SEQ * 132];
  __shared__ float sc[ATILE * 80];
  __shared__ int am[SEQ];
  const float scale = 0.08838834764831845f;  // 1/sqrt(128)

  const float* Kbase = QKV + (size_t)(b * SEQ) * STR + D_MODEL + h * 128;
  for (int idx = threadIdx.x; idx < SEQ * 32; idx += 256) {
    int j = idx >> 5, d4 = (idx & 31) << 2;
    *(float4*)(ks + j * 132 + d4) = *(const float4*)(Kbase + (size_t)j * STR + d4);
  }
  for (int j = threadIdx.x; j < SEQ; j += 256) am[j] = amask[b * SEQ + j];
  __syncthreads();

  int wave = threadIdx.x >> 6, lane = threadIdx.x & 63;
  #pragma unroll
  for (int r = 0; r < 4; ++r) {
    int il = wave * 4 + r;
    int i = it * ATILE + il;
    if (i < SEQ) {
      const float4* qr = (const float4*)(QKV + (size_t)(b * SEQ + i) * STR + h * 128);
      int j1 = lane, j2 = lane + 64;
      float v1 = -1e9f, v2 = -1e9f;
      if (j1 <= i && am[j1]) {
        const float4* kr = (const float4*)(ks + j1 * 132);
        float s = 0.f;
        #pragma unroll 8
        for (int d = 0; d < 32; ++d) {
          float4 a = qr[d], c = kr[d];
          s += a.x*c.x + a.y*c.y + a.z*c.z + a.w*c.w;
        }
        v1 = s * scale;
      }
      if (j2 < SEQ && j2 <= i && am[j2]) {
        const float4* kr = (const float4*)(ks + j2 * 132);
        float s = 0.f;
        #pragma unroll 8
        for (int d = 0; d < 32; ++d) {
          float4 a = qr[d], c = kr[d];
          s += a.x*c.x + a.y*c.y + a.z*c.z + a.w*c.w;
        }
        v2 = s * scale;
      }
      float mx = fmaxf(v1, v2);
      #pragma unroll
      for (int off = 32; off; off >>= 1) mx = fmaxf(mx, __shfl_xor(mx, off));
      float e1 = __expf(v1 - mx);
      float e2 = (j2 < SEQ) ? __expf(v2 - mx) : 0.f;
      float sum = e1 + e2;
      #pragma unroll
      for (int off = 32; off; off >>= 1) sum += __shfl_xor(sum, off);
      float inv = 1.0f / sum;
      sc[il * 80 + j1] = e1 * inv;
      if (j2 < SEQ) sc[il * 80 + j2] = e2 * inv;
    }
  }
  __syncthreads();

  const float* Vbase = QKV + (size_t)(b * SEQ) * STR + 2 * D_MODEL + h * 128;
  for (int idx = threadIdx.x; idx < ATILE * 32; idx += 256) {
    int il = idx >> 5, d4 = (idx & 31) << 2;
    int i = it * ATILE + il;
    if (i >= SEQ) continue;
    float4 acc = {0.f, 0.f, 0.f, 0.f};
    const float* sr = sc + il * 80;
    for (int j = 0; j < SEQ; ++j) {
      float pp = sr[j];
      float4 v = *(const float4*)(Vbase + (size_t)j * STR + d4);
      acc.x += pp * v.x; acc.y += pp * v.y; acc.z += pp * v.z; acc.w += pp * v.w;
    }
    unsigned short* op = O + (size_t)(b * SEQ + i) * D_MODEL + h * 128 + d4;
    op[0] = f2b(acc.x); op[1] = f2b(acc.y); op[2] = f2b(acc.z); op[3] = f2b(acc.w);
  }
}

__global__ void embed_gather(const float* __restrict__ E, const int* __restrict__ ids,
                             float* __restrict__ H)
{
  size_t idx = (size_t)blockIdx.x * 256 + threadIdx.x;
  int m = (int)(idx / D_MODEL);
  int n = (int)(idx % D_MODEL);
  H[idx] = E[(size_t)ids[m] * D_MODEL + n];
}

// GU packed buffer: row stride 16384; g at +0, up at +8192. Output bf16.
__global__ void silu_mul(const float* __restrict__ GU, unsigned short* __restrict__ GB)
{
  size_t id = (size_t)blockIdx.x * 256 + threadIdx.x;
  int m = (int)(id >> 13), n = (int)(id & (F_FFN - 1));
  float g = GU[(size_t)m * 2 * F_FFN + n];
  float u = GU[(size_t)m * 2 * F_FFN + F_FFN + n];
  float sig = 1.0f / (1.0f + expf(-g));
  GB[id] = f2b(g * sig * u);
}

__global__ __launch_bounds__(256) void final_k(
    const float* __restrict__ H, const int* __restrict__ amask,
    const float* __restrict__ W, float* __restrict__ out)
{
  int b = blockIdx.x;
  __shared__ int len;
  if (threadIdx.x == 0) {
    int s = 0;
    for (int j = 0; j < SEQ; ++j) s += amask[b * SEQ + j];
    len = s - 1;
  }
  __syncthreads();
  const float* hr = H + ((size_t)(b * SEQ + len) * D_MODEL);
  float s = 0.f;
  for (int i = threadIdx.x; i < D_MODEL; i += 256) { float v = hr[i]; s += v * v; }
  __shared__ float red[4];
  #pragma unroll
  for (int off = 32; off; off >>= 1) s += __shfl_down(s, off, 64);
  if ((threadIdx.x & 63) == 0) red[threadIdx.x >> 6] = s;
  __syncthreads();
  float tot = red[0] + red[1] + red[2] + red[3];
  float inv = rsqrtf(tot / (float)D_MODEL + 1e-6f);
  for (int i = threadIdx.x; i < D_MODEL; i += 256)
    out[(size_t)b * D_MODEL + i] = hr[i] * inv * W[i];
}

// ---------------------------------------------------------------------------
extern "C" void kernel_launch(void* const* d_in, const int* in_sizes, int n_in,
                              void* d_out, int out_size, void* d_ws, size_t ws_size,
                              hipStream_t stream) {
  const int*   ids     = (const int*)d_in[0];
  const int*   amask   = (const int*)d_in[1];
  const float* embed   = (const float*)d_in[2];
  const float* ln_attn = (const float*)d_in[3];
  const float* ln_mlp  = (const float*)d_in[4];
  const float* ln_fin  = (const float*)d_in[5];
  const int*   qkvC    = (const int*)d_in[6];
  const float* qkvS    = (const float*)d_in[7];
  const float* qkvA    = (const float*)d_in[8];
  const float* qkvB    = (const float*)d_in[9];
  const int*   oC      = (const int*)d_in[10];
  const float* oS      = (const float*)d_in[11];
  const float* oA      = (const float*)d_in[12];
  const float* oB      = (const float*)d_in[13];
  const int*   guC     = (const int*)d_in[14];
  const float* guS     = (const float*)d_in[15];
  const float* guA     = (const float*)d_in[16];
  const float* guB     = (const float*)d_in[17];
  const int*   dnC     = (const int*)d_in[18];
  const float* dnS     = (const float*)d_in[19];
  const float* dnA     = (const float*)d_in[20];
  const float* dnB     = (const float*)d_in[21];
  float* out = (float*)d_out;

  const int M = M_TOK, Mp = M_PAD, D = D_MODEL, F = F_FFN, R = LRANK;
  float* p = (float*)d_ws;
  float* h    = p; p += (size_t)Mp * D;
  float* qkv  = p; p += (size_t)Mp * 3 * D;   // also reused as gbf (bf16) later
  float* gu   = p; p += (size_t)Mp * 2 * F;
  float* t    = p; p += (size_t)Mp * 48;
  float* cosT = p; p += SEQ * 64;
  float* sinT = p; p += SEQ * 64;
  unsigned short* xbf = (unsigned short*)p; p += (size_t)Mp * D / 2;
  unsigned short* gbf = (unsigned short*)qkv;   // Mp*F ushorts <= Mp*3*D floats
  unsigned short* wbuf = (unsigned short*)p;    // bf16 weight buffer, max 2*F*D elems
  p += (size_t)2 * F * D / 2;

  rope_table<<<(SEQ*64 + 63)/64, 64, 0, stream>>>(cosT, sinT);
  embed_gather<<<(M * D)/256, 256, 0, stream>>>(embed, ids, h);

  const int mb = Mp / 128;

  for (int l = 0; l < NLAYER; ++l) {
    // ---- attention ----
    rmsnorm_k<<<M, 256, 0, stream>>>(h, ln_attn + (size_t)l * D, xbf, D);
    lora1<<<dim3(M/4, 3), 256, 0, stream>>>(xbf, qkvA + (size_t)l*3*R*D, t, D);
    mat_w<<<4096, 256, 0, stream>>>(qkvC + (size_t)l*3*D*D, qkvS + (size_t)l*3*D*(D/64),
                                    wbuf, D, (long)3*D*D/8);
    gemm_bf<<<mb * (3*D/128), 256, 0, stream>>>(
        xbf, wbuf, qkv, mb, 3*D, D, 0, 1,
        t, qkvB + (size_t)l*3*D*R, 11, 48);
    rope_apply<<<((size_t)M*NHEAD*64 + 255)/256, 256, 0, stream>>>(qkv, cosT, sinT);
    attn_k<<<dim3(BATCH*NHEAD, (SEQ + ATILE - 1)/ATILE), 256, 0, stream>>>(qkv, amask, xbf);
    mat_w<<<2048, 256, 0, stream>>>(oC + (size_t)l*D*D, oS + (size_t)l*D*(D/64),
                                    wbuf, D, (long)D*D/8);
    gemm_bf<<<mb * (D/128) * 8, 256, 0, stream>>>(
        xbf, wbuf, h, mb, D, D, 1, 8, nullptr, nullptr, 0, 0);
    lora1<<<dim3(M/4, 1), 256, 0, stream>>>(xbf, oA + (size_t)l*R*D, t, D);
    lora2<<<dim3(D/256, M/8), 256, 0, stream>>>(h, t, oB + (size_t)l*D*R, D, 11, 16);

    // ---- MLP ----
    rmsnorm_k<<<M, 256, 0, stream>>>(h, ln_mlp + (size_t)l * D, xbf, D);
    lora1<<<dim3(M/4, 2), 256, 0, stream>>>(xbf, guA + (size_t)l*2*R*D, t, D);
    mat_w<<<4096, 256, 0, stream>>>(guC + (size_t)l*2*F*D, guS + (size_t)l*2*F*(D/64),
                                    wbuf, D, (long)2*F*D/8);
    gemm_bf<<<mb * (2*F/128), 256, 0, stream>>>(
        xbf, wbuf, gu, mb, 2*F, D, 0, 1,
        t, guB + (size_t)l*2*F*R, 13, 32);
    silu_mul<<<((size_t)M * F)/256, 256, 0, stream>>>(gu, gbf);
    mat_w<<<4096, 256, 0, stream>>>(dnC + (size_t)l*D*F, dnS + (size_t)l*D*(F/64),
                                    wbuf, F, (long)D*F/8);
    gemm_bf<<<mb * (D/128) * 8, 256, 0, stream>>>(
        gbf, wbuf, h, mb, D, F, 1, 8, nullptr, nullptr, 0, 0);
    lora1<<<dim3(M/4, 1), 256, 0, stream>>>(gbf, dnA + (size_t)l*R*F, t, F);
    lora2<<<dim3(D/256, M/8), 256, 0, stream>>>(h, t, dnB + (size_t)l*D*R, D, 11, 16);
  }
  final_k<<<BATCH, 256, 0, stream>>>(h, amask, ln_fin, out);
}

// Round 11
// 1233.625 us; speedup vs baseline: 1.2993x; 1.0829x over previous
//
#include <hip/hip_runtime.h>
#include <cstdint>
#include <cstddef>

#define M_TOK   1232      // B*S
#define M_PAD   1280
#define D_MODEL 2048
#define F_FFN   8192
#define SEQ     77
#define BATCH   16
#define NHEAD   16
#define LRANK   16
#define NLAYER  2
#define ATILE   16

typedef short bf16x8 __attribute__((ext_vector_type(8)));
typedef float f32x4  __attribute__((ext_vector_type(4)));

__device__ __constant__ float NF4C[16] = {
  -1.0f, -0.6961928009986877f, -0.5250730514526367f, -0.39491748809814453f,
  -0.28444138169288635f, -0.18477343022823334f, -0.09105003625154495f, 0.0f,
  0.07958029955625534f, 0.16093020141124725f, 0.24611230194568634f,
  0.33791524171829224f, 0.44070982933044434f, 0.5626170039176941f,
  0.723855197429657f, 1.0f };

__device__ inline unsigned short f2b(float f) {
  unsigned u = __builtin_bit_cast(unsigned, f);
  u += 0x7FFFu + ((u >> 16) & 1u);   // RNE
  return (unsigned short)(u >> 16);
}
__device__ inline float b2f(unsigned short s) {
  return __builtin_bit_cast(float, ((unsigned)s) << 16);
}

// ---------------------------------------------------------------------------
// Materialize bf16 weights: W[rd][k] = bf16(NF4[C[src][k]] * AM[src][k/64])
// ilv: dest row rd maps to src row (rd&1)*F_FFN + (rd>>1)  (gate/up interleave)
// ---------------------------------------------------------------------------
__global__ __launch_bounds__(256) void mat_w(
    const int* __restrict__ C, const float* __restrict__ AM,
    unsigned short* __restrict__ W, int K, long total8, int ilv)
{
  __shared__ float tb[16];
  if (threadIdx.x < 16) tb[threadIdx.x] = NF4C[threadIdx.x];
  __syncthreads();
  const int KB = K >> 6;
  for (long i = (long)blockIdx.x * 256 + threadIdx.x; i < total8;
       i += (long)gridDim.x * 256) {
    long e = i << 3;
    int rd = (int)(e / K), k = (int)(e - (long)rd * K);
    int srcn = ilv ? ((rd & 1) * F_FFN + (rd >> 1)) : rd;
    float am = AM[(size_t)srcn * KB + (k >> 6)];
    const int4* cp = (const int4*)(C + (size_t)srcn * K + k);
    int4 a = cp[0], b = cp[1];
    uint4 o;
    o.x = (unsigned)f2b(tb[a.x] * am) | ((unsigned)f2b(tb[a.y] * am) << 16);
    o.y = (unsigned)f2b(tb[a.z] * am) | ((unsigned)f2b(tb[a.w] * am) << 16);
    o.z = (unsigned)f2b(tb[b.x] * am) | ((unsigned)f2b(tb[b.y] * am) << 16);
    o.w = (unsigned)f2b(tb[b.z] * am) | ((unsigned)f2b(tb[b.w] * am) << 16);
    *(uint4*)(W + e) = o;
  }
}

// ---------------------------------------------------------------------------
// bf16 GEMM, m97 structure: single-buffered 32KB LDS, two barriers per
// K-tile, global_load_lds staging with pre-swizzled source. (256,2): VGPR~76.
// Epilogues: plain / +=, split-K atomics, fused LoRA-2 (splitk==1), or
// GUMODE: gate/up interleaved cols -> silu(g)*u written as bf16 to GB.
// ---------------------------------------------------------------------------
__global__ __launch_bounds__(256, 2) void gemm_bf(
    const unsigned short* __restrict__ X, const unsigned short* __restrict__ W,
    float* __restrict__ O, int mb, int N, int K, int acc_mode, int splitk,
    const float* __restrict__ T, const float* __restrict__ Bm, int sh, int nr,
    int gum, unsigned short* __restrict__ GB)
{
  __shared__ __align__(16) unsigned short xs[128 * 64];
  __shared__ __align__(16) unsigned short ws[128 * 64];

  int tid = threadIdx.x;

  // XCD-chunked bijective swizzle
  int nwg = gridDim.x;
  int q8 = nwg >> 3, r8 = nwg & 7;
  int xcd = blockIdx.x & 7, pos = blockIdx.x >> 3;
  int wgid = (xcd < r8) ? (xcd * (q8 + 1) + pos)
                        : (r8 * (q8 + 1) + (xcd - r8) * q8 + pos);
  int nb = N >> 7;
  int per = mb * nb;
  int slice = wgid / per; int rem = wgid - slice * per;
  int nblk = rem / mb, mblk = rem - nblk * mb;
  int row0 = mblk << 7, col0 = nblk << 7;
  int KBtot = K >> 6, kcnt = KBtot / splitk, kbeg = slice * kcnt;

  int wave = tid >> 6, lane = tid & 63;
  int fr = lane & 15, fg = lane >> 4, s7 = fr & 7;
  int wm = (wave >> 1) * 64, wn = (wave & 1) * 64;
  int xg = lane >> 3;
  int xcol = (((lane & 7) ^ (xg & 7)) << 3);

  const unsigned short* Xbase = X + (size_t)row0 * K + (size_t)kbeg * 64;
  const unsigned short* Wbase = W + (size_t)col0 * K + (size_t)kbeg * 64;

  f32x4 accm[4][4];
  #pragma unroll
  for (int i = 0; i < 4; ++i)
    #pragma unroll
    for (int j = 0; j < 4; ++j) accm[i][j] = (f32x4){0.f, 0.f, 0.f, 0.f};

  auto stage = [&](int t) {
    const unsigned short* xb = Xbase + (size_t)t * 64;
    const unsigned short* wb = Wbase + (size_t)t * 64;
    #pragma unroll
    for (int p2 = 0; p2 < 4; ++p2) {
      int c = wave * 4 + p2;
      const unsigned short* gp = xb + (size_t)(c * 8 + xg) * K + xcol;
      __builtin_amdgcn_global_load_lds(
          (const __attribute__((address_space(1))) unsigned int*)gp,
          (__attribute__((address_space(3))) unsigned int*)(xs + c * 512),
          16, 0, 0);
    }
    #pragma unroll
    for (int p2 = 0; p2 < 4; ++p2) {
      int c = wave * 4 + p2;
      const unsigned short* gp = wb + (size_t)(c * 8 + xg) * K + xcol;
      __builtin_amdgcn_global_load_lds(
          (const __attribute__((address_space(1))) unsigned int*)gp,
          (__attribute__((address_space(3))) unsigned int*)(ws + c * 512),
          16, 0, 0);
    }
  };
  auto compute = [&]() {
    bf16x8 b0[4], b1[4];
    #pragma unroll
    for (int ni = 0; ni < 4; ++ni) {
      const unsigned short* wr = ws + (wn + ni * 16 + fr) * 64;
      b0[ni] = *(const bf16x8*)(wr + ((fg ^ s7) << 3));
      b1[ni] = *(const bf16x8*)(wr + (((4 | fg) ^ s7) << 3));
    }
    #pragma unroll
    for (int mi = 0; mi < 4; ++mi) {
      const unsigned short* xr = xs + (wm + mi * 16 + fr) * 64;
      bf16x8 a0 = *(const bf16x8*)(xr + ((fg ^ s7) << 3));
      bf16x8 a1 = *(const bf16x8*)(xr + (((4 | fg) ^ s7) << 3));
      #pragma unroll
      for (int ni = 0; ni < 4; ++ni) {
        accm[mi][ni] = __builtin_amdgcn_mfma_f32_16x16x32_bf16(
            a0, b0[ni], accm[mi][ni], 0, 0, 0);
        accm[mi][ni] = __builtin_amdgcn_mfma_f32_16x16x32_bf16(
            a1, b1[ni], accm[mi][ni], 0, 0, 0);
      }
    }
  };

  stage(0);
  for (int t = 0; t < kcnt; ++t) {
    __syncthreads();
    compute();
    if (t + 1 < kcnt) {
      __syncthreads();
      stage(t + 1);
    }
  }

  if (gum) {
    // ---- GUMODE epilogue: cols interleaved gate/up; out = silu(g)*u ----
    float* Tt = (float*)&xs[0];   // 128 x 32
    float* Bt = (float*)&ws[0];   // 128 x 16 (interleaved rows)
    __syncthreads();
    for (int idx = tid; idx < 128 * 32; idx += 256) {
      int rr = idx >> 5, c = idx & 31;
      int gm = row0 + rr;
      Tt[idx] = (gm < M_TOK) ? T[(size_t)gm * 32 + c] : 0.f;
    }
    for (int idx = tid; idx < 128 * 16; idx += 256) {
      int rr = idx >> 4, c = idx & 15;
      int type = rr & 1, nrow = (col0 + rr) >> 1;
      Bt[idx] = Bm[((size_t)type * F_FFN + nrow) * LRANK + c];
    }
    __syncthreads();
    #pragma unroll
    for (int mi = 0; mi < 4; ++mi)
      #pragma unroll
      for (int ni = 0; ni < 4; ++ni) {
        int gm0 = row0 + wm + mi * 16 + fg * 4;
        int gnl = wn + ni * 16 + fr;
        #pragma unroll
        for (int r = 0; r < 4; ++r) {
          int gm = gm0 + r;
          float vv = accm[mi][ni][r];
          const float* tr = Tt + (wm + mi * 16 + fg * 4 + r) * 32 + ((gnl & 1) << 4);
          const float* br = Bt + gnl * 16;
          float s = 0.f;
          #pragma unroll
          for (int c = 0; c < 16; ++c) s += tr[c] * br[c];
          vv += 2.0f * s;
          float prt = __shfl_xor(vv, 1);
          if (gm < M_TOK && !(fr & 1)) {
            float sig = 1.0f / (1.0f + expf(-vv));
            GB[(size_t)gm * F_FFN + ((col0 + gnl) >> 1)] = f2b(vv * sig * prt);
          }
        }
      }
    return;
  }

  // optional fused LoRA-2: stage T[128][16], Bm[128][16] into (free) LDS
  float* Tt = (float*)&xs[0];
  float* Bt = (float*)&ws[0];
  if (T) {
    __syncthreads();
    int toff = (col0 >> sh) << 4;
    for (int idx = tid; idx < 128 * 16; idx += 256) {
      int rr = idx >> 4, c = idx & 15;
      int gm = row0 + rr;
      Tt[idx] = (gm < M_TOK) ? T[(size_t)gm * nr + toff + c] : 0.f;
      Bt[idx] = Bm[(size_t)(col0 + rr) * LRANK + c];
    }
    __syncthreads();
  }

  #pragma unroll
  for (int mi = 0; mi < 4; ++mi)
    #pragma unroll
    for (int ni = 0; ni < 4; ++ni) {
      int gm0 = row0 + wm + mi * 16 + fg * 4;
      int gnl = wn + ni * 16 + fr;
      int gn = col0 + gnl;
      #pragma unroll
      for (int r = 0; r < 4; ++r) {
        int gm = gm0 + r;
        if (gm < M_TOK) {
          size_t idx = (size_t)gm * N + gn;
          float vv = accm[mi][ni][r];
          if (T) {
            const float* tr = Tt + (wm + mi * 16 + fg * 4 + r) * 16;
            const float* br = Bt + gnl * 16;
            float s = 0.f;
            #pragma unroll
            for (int c = 0; c < 16; ++c) s += tr[c] * br[c];
            vv += 2.0f * s;
          }
          if (splitk > 1)       atomicAdd(&O[idx], vv);
          else if (acc_mode)    O[idx] += vv;
          else                  O[idx] = vv;
        }
      }
    }
}

// ---------------------------------------------------------------------------
// LoRA stage 1, 4 m-rows per block: T[m][bi*16+g] = sum_k X[m][k]*A[bi][g][k]
__global__ __launch_bounds__(256) void lora1(
    const unsigned short* __restrict__ X, const float* __restrict__ A,
    float* __restrict__ T, int K)
{
  int m0 = blockIdx.x * 4, bi = blockIdx.y, nmat = gridDim.y;
  int g = threadIdx.x >> 4, l16 = threadIdx.x & 15;
  const float* ar = A + (size_t)bi * LRANK * K + (size_t)g * K;
  const unsigned short* x0 = X + (size_t)m0 * K;
  float s0 = 0.f, s1 = 0.f, s2 = 0.f, s3 = 0.f;
  for (int kk = l16 * 4; kk < K; kk += 64) {
    float4 av = *(const float4*)(ar + kk);
    ushort4 v0 = *(const ushort4*)(x0 + kk);
    ushort4 v1 = *(const ushort4*)(x0 + K + kk);
    ushort4 v2 = *(const ushort4*)(x0 + 2 * K + kk);
    ushort4 v3 = *(const ushort4*)(x0 + 3 * K + kk);
    s0 += b2f(v0.x)*av.x + b2f(v0.y)*av.y + b2f(v0.z)*av.z + b2f(v0.w)*av.w;
    s1 += b2f(v1.x)*av.x + b2f(v1.y)*av.y + b2f(v1.z)*av.z + b2f(v1.w)*av.w;
    s2 += b2f(v2.x)*av.x + b2f(v2.y)*av.y + b2f(v2.z)*av.z + b2f(v2.w)*av.w;
    s3 += b2f(v3.x)*av.x + b2f(v3.y)*av.y + b2f(v3.z)*av.z + b2f(v3.w)*av.w;
  }
  #pragma unroll
  for (int off = 8; off; off >>= 1) {
    s0 += __shfl_down(s0, off, 16);
    s1 += __shfl_down(s1, off, 16);
    s2 += __shfl_down(s2, off, 16);
    s3 += __shfl_down(s3, off, 16);
  }
  if (l16 == 0) {
    size_t base = ((size_t)m0 * nmat + bi) * LRANK + g;
    size_t rs = (size_t)nmat * LRANK;
    T[base] = s0; T[base + rs] = s1; T[base + 2*rs] = s2; T[base + 3*rs] = s3;
  }
}

// LoRA stage 2 (separate path for split-K GEMMs), 8 m-rows per block
__global__ __launch_bounds__(256) void lora2(
    float* __restrict__ O, const float* __restrict__ T,
    const float* __restrict__ Bm, int N, int sh, int nr)
{
  int m0 = blockIdx.y * 8;
  int n = blockIdx.x * 256 + threadIdx.x;
  __shared__ float ts[8 * 48];
  for (int i = threadIdx.x; i < 8 * nr; i += 256)
    ts[(i / nr) * 48 + (i % nr)] = T[(size_t)(m0 + i / nr) * nr + (i % nr)];
  __syncthreads();
  const float4* br = (const float4*)(Bm + (size_t)n * LRANK);
  float4 b0 = br[0], b1 = br[1], b2 = br[2], b3 = br[3];
  int toff = ((n >> sh) << 4);
  #pragma unroll
  for (int mi = 0; mi < 8; ++mi) {
    const float* tsb = ts + mi * 48 + toff;
    float s = b0.x*tsb[0] + b0.y*tsb[1] + b0.z*tsb[2] + b0.w*tsb[3]
            + b1.x*tsb[4] + b1.y*tsb[5] + b1.z*tsb[6] + b1.w*tsb[7]
            + b2.x*tsb[8] + b2.y*tsb[9] + b2.z*tsb[10] + b2.w*tsb[11]
            + b3.x*tsb[12] + b3.y*tsb[13] + b3.z*tsb[14] + b3.w*tsb[15];
    O[(size_t)(m0 + mi) * N + n] += 2.0f * s;
  }
}

// ---------------------------------------------------------------------------
__global__ __launch_bounds__(256) void rmsnorm_k(
    const float* __restrict__ H, const float* __restrict__ W,
    unsigned short* __restrict__ X, int D)
{
  int m = blockIdx.x;
  const float* hr = H + (size_t)m * D;
  float s = 0.f;
  for (int i = threadIdx.x; i < D; i += 256) { float v = hr[i]; s += v * v; }
  __shared__ float red[4];
  #pragma unroll
  for (int off = 32; off; off >>= 1) s += __shfl_down(s, off, 64);
  if ((threadIdx.x & 63) == 0) red[threadIdx.x >> 6] = s;
  __syncthreads();
  float tot = red[0] + red[1] + red[2] + red[3];
  float inv = rsqrtf(tot / (float)D + 1e-6f);
  for (int i = threadIdx.x; i < D; i += 256)
    X[(size_t)m * D + i] = f2b(hr[i] * inv * W[i]);
}

__global__ void rope_table(float* __restrict__ cosT, float* __restrict__ sinT)
{
  int idx = blockIdx.x * 64 + threadIdx.x;
  if (idx >= SEQ * 64) return;
  int s = idx >> 6, j = idx & 63;
  float inv = powf(10000.0f, -(float)(2 * j) / 128.0f);
  float f = (float)s * inv;
  cosT[idx] = cosf(f);
  sinT[idx] = sinf(f);
}

// ---------------------------------------------------------------------------
// Attention with fused RoPE: grid (B*H, 5 row-tiles of 16). Roped K and
// roped Q tile staged in LDS (pad 132), wave-parallel softmax, PV from L2.
// ---------------------------------------------------------------------------
__global__ __launch_bounds__(256) void attn_k(
    const float* __restrict__ QKV, const int* __restrict__ amask,
    const float* __restrict__ cosT, const float* __restrict__ sinT,
    unsigned short* __restrict__ O)
{
  int bh = blockIdx.x, it = blockIdx.y;
  int b = bh >> 4, h = bh & (NHEAD - 1);
  const int STR = 3 * D_MODEL;
  __shared__ float ks[SEQ * 132];
  __shared__ float qs[ATILE * 132];
  __shared__ float sc[ATILE * 80];
  __shared__ int am[SEQ];
  const float scale = 0.08838834764831845f;  // 1/sqrt(128)

  // stage roped K (all rows)
  const float* Kb = QKV + (size_t)(b * SEQ) * STR + D_MODEL + h * 128;
  for (int idx = threadIdx.x; idx < SEQ * 16; idx += 256) {
    int j = idx >> 4, dq = (idx & 15) << 2;
    float4 a = *(const float4*)(Kb + (size_t)j * STR + dq);
    float4 bb = *(const float4*)(Kb + (size_t)j * STR + dq + 64);
    float4 c4 = *(const float4*)(cosT + j * 64 + dq);
    float4 s4 = *(const float4*)(sinT + j * 64 + dq);
    float* kr = ks + j * 132 + dq;
    kr[0] = a.x*c4.x - bb.x*s4.x; kr[1] = a.y*c4.y - bb.y*s4.y;
    kr[2] = a.z*c4.z - bb.z*s4.z; kr[3] = a.w*c4.w - bb.w*s4.w;
    kr[64] = bb.x*c4.x + a.x*s4.x; kr[65] = bb.y*c4.y + a.y*s4.y;
    kr[66] = bb.z*c4.z + a.z*s4.z; kr[67] = bb.w*c4.w + a.w*s4.w;
  }
  // stage roped Q (this tile's rows)
  const float* Qb = QKV + (size_t)(b * SEQ) * STR + h * 128;
  for (int idx = threadIdx.x; idx < ATILE * 16; idx += 256) {
    int il = idx >> 4, dq = (idx & 15) << 2;
    int i = it * ATILE + il;
    if (i < SEQ) {
      float4 a = *(const float4*)(Qb + (size_t)i * STR + dq);
      float4 bb = *(const float4*)(Qb + (size_t)i * STR + dq + 64);
      float4 c4 = *(const float4*)(cosT + i * 64 + dq);
      float4 s4 = *(const float4*)(sinT + i * 64 + dq);
      float* qr = qs + il * 132 + dq;
      qr[0] = a.x*c4.x - bb.x*s4.x; qr[1] = a.y*c4.y - bb.y*s4.y;
      qr[2] = a.z*c4.z - bb.z*s4.z; qr[3] = a.w*c4.w - bb.w*s4.w;
      qr[64] = bb.x*c4.x + a.x*s4.x; qr[65] = bb.y*c4.y + a.y*s4.y;
      qr[66] = bb.z*c4.z + a.z*s4.z; qr[67] = bb.w*c4.w + a.w*s4.w;
    }
  }
  for (int j = threadIdx.x; j < SEQ; j += 256) am[j] = amask[b * SEQ + j];
  __syncthreads();

  int wave = threadIdx.x >> 6, lane = threadIdx.x & 63;
  #pragma unroll
  for (int r = 0; r < 4; ++r) {
    int il = wave * 4 + r;
    int i = it * ATILE + il;
    if (i < SEQ) {
      const float4* qr = (const float4*)(qs + il * 132);
      int j1 = lane, j2 = lane + 64;
      float v1 = -1e9f, v2 = -1e9f;
      if (j1 <= i && am[j1]) {
        const float4* kr = (const float4*)(ks + j1 * 132);
        float s = 0.f;
        #pragma unroll 8
        for (int d = 0; d < 32; ++d) {
          float4 a = qr[d], c = kr[d];
          s += a.x*c.x + a.y*c.y + a.z*c.z + a.w*c.w;
        }
        v1 = s * scale;
      }
      if (j2 < SEQ && j2 <= i && am[j2]) {
        const float4* kr = (const float4*)(ks + j2 * 132);
        float s = 0.f;
        #pragma unroll 8
        for (int d = 0; d < 32; ++d) {
          float4 a = qr[d], c = kr[d];
          s += a.x*c.x + a.y*c.y + a.z*c.z + a.w*c.w;
        }
        v2 = s * scale;
      }
      float mx = fmaxf(v1, v2);
      #pragma unroll
      for (int off = 32; off; off >>= 1) mx = fmaxf(mx, __shfl_xor(mx, off));
      float e1 = __expf(v1 - mx);
      float e2 = (j2 < SEQ) ? __expf(v2 - mx) : 0.f;
      float sum = e1 + e2;
      #pragma unroll
      for (int off = 32; off; off >>= 1) sum += __shfl_xor(sum, off);
      float inv = 1.0f / sum;
      sc[il * 80 + j1] = e1 * inv;
      if (j2 < SEQ) sc[il * 80 + j2] = e2 * inv;
    }
  }
  __syncthreads();

  const float* Vbase = QKV + (size_t)(b * SEQ) * STR + 2 * D_MODEL + h * 128;
  for (int idx = threadIdx.x; idx < ATILE * 32; idx += 256) {
    int il = idx >> 5, d4 = (idx & 31) << 2;
    int i = it * ATILE + il;
    if (i >= SEQ) continue;
    float4 acc = {0.f, 0.f, 0.f, 0.f};
    const float* sr = sc + il * 80;
    for (int j = 0; j < SEQ; ++j) {
      float pp = sr[j];
      float4 v = *(const float4*)(Vbase + (size_t)j * STR + d4);
      acc.x += pp * v.x; acc.y += pp * v.y; acc.z += pp * v.z; acc.w += pp * v.w;
    }
    unsigned short* op = O + (size_t)(b * SEQ + i) * D_MODEL + h * 128 + d4;
    op[0] = f2b(acc.x); op[1] = f2b(acc.y); op[2] = f2b(acc.z); op[3] = f2b(acc.w);
  }
}

__global__ void embed_gather(const float* __restrict__ E, const int* __restrict__ ids,
                             float* __restrict__ H)
{
  size_t idx = (size_t)blockIdx.x * 256 + threadIdx.x;
  int m = (int)(idx / D_MODEL);
  int n = (int)(idx % D_MODEL);
  H[idx] = E[(size_t)ids[m] * D_MODEL + n];
}

__global__ __launch_bounds__(256) void final_k(
    const float* __restrict__ H, const int* __restrict__ amask,
    const float* __restrict__ W, float* __restrict__ out)
{
  int b = blockIdx.x;
  __shared__ int len;
  if (threadIdx.x == 0) {
    int s = 0;
    for (int j = 0; j < SEQ; ++j) s += amask[b * SEQ + j];
    len = s - 1;
  }
  __syncthreads();
  const float* hr = H + ((size_t)(b * SEQ + len) * D_MODEL);
  float s = 0.f;
  for (int i = threadIdx.x; i < D_MODEL; i += 256) { float v = hr[i]; s += v * v; }
  __shared__ float red[4];
  #pragma unroll
  for (int off = 32; off; off >>= 1) s += __shfl_down(s, off, 64);
  if ((threadIdx.x & 63) == 0) red[threadIdx.x >> 6] = s;
  __syncthreads();
  float tot = red[0] + red[1] + red[2] + red[3];
  float inv = rsqrtf(tot / (float)D_MODEL + 1e-6f);
  for (int i = threadIdx.x; i < D_MODEL; i += 256)
    out[(size_t)b * D_MODEL + i] = hr[i] * inv * W[i];
}

// ---------------------------------------------------------------------------
extern "C" void kernel_launch(void* const* d_in, const int* in_sizes, int n_in,
                              void* d_out, int out_size, void* d_ws, size_t ws_size,
                              hipStream_t stream) {
  const int*   ids     = (const int*)d_in[0];
  const int*   amask   = (const int*)d_in[1];
  const float* embed   = (const float*)d_in[2];
  const float* ln_attn = (const float*)d_in[3];
  const float* ln_mlp  = (const float*)d_in[4];
  const float* ln_fin  = (const float*)d_in[5];
  const int*   qkvC    = (const int*)d_in[6];
  const float* qkvS    = (const float*)d_in[7];
  const float* qkvA    = (const float*)d_in[8];
  const float* qkvB    = (const float*)d_in[9];
  const int*   oC      = (const int*)d_in[10];
  const float* oS      = (const float*)d_in[11];
  const float* oA      = (const float*)d_in[12];
  const float* oB      = (const float*)d_in[13];
  const int*   guC     = (const int*)d_in[14];
  const float* guS     = (const float*)d_in[15];
  const float* guA     = (const float*)d_in[16];
  const float* guB     = (const float*)d_in[17];
  const int*   dnC     = (const int*)d_in[18];
  const float* dnS     = (const float*)d_in[19];
  const float* dnA     = (const float*)d_in[20];
  const float* dnB     = (const float*)d_in[21];
  float* out = (float*)d_out;

  const int M = M_TOK, Mp = M_PAD, D = D_MODEL, F = F_FFN, R = LRANK;
  float* p = (float*)d_ws;
  float* h    = p; p += (size_t)Mp * D;
  float* qkv  = p; p += (size_t)Mp * 3 * D;
  float* t    = p; p += (size_t)Mp * 48;
  float* cosT = p; p += SEQ * 64;
  float* sinT = p; p += SEQ * 64;
  unsigned short* xbf = (unsigned short*)p; p += (size_t)Mp * D / 2;
  unsigned short* gbf = (unsigned short*)p; p += (size_t)Mp * F / 2;
  unsigned short* wbuf = (unsigned short*)p;    // bf16 weight buffer
  p += (size_t)2 * F * D / 2;

  rope_table<<<(SEQ*64 + 63)/64, 64, 0, stream>>>(cosT, sinT);
  embed_gather<<<(M * D)/256, 256, 0, stream>>>(embed, ids, h);

  const int mb = Mp / 128;

  for (int l = 0; l < NLAYER; ++l) {
    // ---- attention ----
    rmsnorm_k<<<M, 256, 0, stream>>>(h, ln_attn + (size_t)l * D, xbf, D);
    lora1<<<dim3(M/4, 3), 256, 0, stream>>>(xbf, qkvA + (size_t)l*3*R*D, t, D);
    mat_w<<<4096, 256, 0, stream>>>(qkvC + (size_t)l*3*D*D, qkvS + (size_t)l*3*D*(D/64),
                                    wbuf, D, (long)3*D*D/8, 0);
    gemm_bf<<<mb * (3*D/128), 256, 0, stream>>>(
        xbf, wbuf, qkv, mb, 3*D, D, 0, 1,
        t, qkvB + (size_t)l*3*D*R, 11, 48, 0, nullptr);
    attn_k<<<dim3(BATCH*NHEAD, (SEQ + ATILE - 1)/ATILE), 256, 0, stream>>>(
        qkv, amask, cosT, sinT, xbf);
    mat_w<<<2048, 256, 0, stream>>>(oC + (size_t)l*D*D, oS + (size_t)l*D*(D/64),
                                    wbuf, D, (long)D*D/8, 0);
    gemm_bf<<<mb * (D/128) * 4, 256, 0, stream>>>(
        xbf, wbuf, h, mb, D, D, 1, 4, nullptr, nullptr, 0, 0, 0, nullptr);
    lora1<<<dim3(M/4, 1), 256, 0, stream>>>(xbf, oA + (size_t)l*R*D, t, D);
    lora2<<<dim3(D/256, M/8), 256, 0, stream>>>(h, t, oB + (size_t)l*D*R, D, 11, 16);

    // ---- MLP ----
    rmsnorm_k<<<M, 256, 0, stream>>>(h, ln_mlp + (size_t)l * D, xbf, D);
    lora1<<<dim3(M/4, 2), 256, 0, stream>>>(xbf, guA + (size_t)l*2*R*D, t, D);
    mat_w<<<4096, 256, 0, stream>>>(guC + (size_t)l*2*F*D, guS + (size_t)l*2*F*(D/64),
                                    wbuf, D, (long)2*F*D/8, 1);
    gemm_bf<<<mb * (2*F/128), 256, 0, stream>>>(
        xbf, wbuf, nullptr, mb, 2*F, D, 0, 1,
        t, guB + (size_t)l*2*F*R, 0, 32, 1, gbf);
    mat_w<<<4096, 256, 0, stream>>>(dnC + (size_t)l*D*F, dnS + (size_t)l*D*(F/64),
                                    wbuf, F, (long)D*F/8, 0);
    gemm_bf<<<mb * (D/128) * 8, 256, 0, stream>>>(
        gbf, wbuf, h, mb, D, F, 1, 8, nullptr, nullptr, 0, 0, 0, nullptr);
    lora1<<<dim3(M/4, 1), 256, 0, stream>>>(gbf, dnA + (size_t)l*R*F, t, F);
    lora2<<<dim3(D/256, M/8), 256, 0, stream>>>(h, t, dnB + (size_t)l*D*R, D, 11, 16);
  }
  final_k<<<BATCH, 256, 0, stream>>>(h, amask, ln_fin, out);
}

// Round 12
// 1191.654 us; speedup vs baseline: 1.3450x; 1.0352x over previous
//
#include <hip/hip_runtime.h>
#include <cstdint>
#include <cstddef>

#define M_TOK   1232      // B*S
#define M_PAD   1280
#define D_MODEL 2048
#define F_FFN   8192
#define SEQ     77
#define BATCH   16
#define NHEAD   16
#define LRANK   16
#define NLAYER  2
#define ATILE   16
#define MWB     512       // carry (mat_w) blocks appended to GEMM grids

typedef short bf16x8 __attribute__((ext_vector_type(8)));
typedef float f32x4  __attribute__((ext_vector_type(4)));

__device__ __constant__ float NF4C[16] = {
  -1.0f, -0.6961928009986877f, -0.5250730514526367f, -0.39491748809814453f,
  -0.28444138169288635f, -0.18477343022823334f, -0.09105003625154495f, 0.0f,
  0.07958029955625534f, 0.16093020141124725f, 0.24611230194568634f,
  0.33791524171829224f, 0.44070982933044434f, 0.5626170039176941f,
  0.723855197429657f, 1.0f };

__device__ inline unsigned short f2b(float f) {
  unsigned u = __builtin_bit_cast(unsigned, f);
  u += 0x7FFFu + ((u >> 16) & 1u);   // RNE
  return (unsigned short)(u >> 16);
}
__device__ inline float b2f(unsigned short s) {
  return __builtin_bit_cast(float, ((unsigned)s) << 16);
}

// ---------------------------------------------------------------------------
// Standalone weight materialization (prologue only).
// W[rd][k] = bf16(NF4[C[src][k]] * AM[src][k/64]); ilv: rd -> (rd&1)*F + rd>>1
// ---------------------------------------------------------------------------
__global__ __launch_bounds__(256) void mat_w(
    const int* __restrict__ C, const float* __restrict__ AM,
    unsigned short* __restrict__ W, int K, long total8, int ilv)
{
  __shared__ float tb[16];
  if (threadIdx.x < 16) tb[threadIdx.x] = NF4C[threadIdx.x];
  __syncthreads();
  const int KB = K >> 6;
  for (long i = (long)blockIdx.x * 256 + threadIdx.x; i < total8;
       i += (long)gridDim.x * 256) {
    long e = i << 3;
    int rd = (int)(e / K), k = (int)(e - (long)rd * K);
    int srcn = ilv ? ((rd & 1) * F_FFN + (rd >> 1)) : rd;
    float am = AM[(size_t)srcn * KB + (k >> 6)];
    const int4* cp = (const int4*)(C + (size_t)srcn * K + k);
    int4 a = cp[0], b = cp[1];
    uint4 o;
    o.x = (unsigned)f2b(tb[a.x] * am) | ((unsigned)f2b(tb[a.y] * am) << 16);
    o.y = (unsigned)f2b(tb[a.z] * am) | ((unsigned)f2b(tb[a.w] * am) << 16);
    o.z = (unsigned)f2b(tb[b.x] * am) | ((unsigned)f2b(tb[b.y] * am) << 16);
    o.w = (unsigned)f2b(tb[b.z] * am) | ((unsigned)f2b(tb[b.w] * am) << 16);
    *(uint4*)(W + e) = o;
  }
}

// ---------------------------------------------------------------------------
// bf16 GEMM (m97 single-buffer 32KB structure) + carry blocks: blocks with
// bid >= Ggemm run the NEXT weight's dequant-materialization (grid-stride),
// overlapping memory-bound weight prep under the compute-bound GEMM.
// Epilogues: plain/+=/split-K atomics/fused LoRA-2/GUMODE(silu(g)*u->bf16).
// ---------------------------------------------------------------------------
__global__ __launch_bounds__(256, 2) void gemm_bf(
    const unsigned short* __restrict__ X, const unsigned short* __restrict__ W,
    float* __restrict__ O, int mb, int N, int K, int acc_mode, int splitk,
    const float* __restrict__ T, const float* __restrict__ Bm, int sh, int nr,
    int gum, unsigned short* __restrict__ GB,
    const int* __restrict__ C2, const float* __restrict__ AM2,
    unsigned short* __restrict__ W2, int K2, long total8_2, int ilv2, int Ggemm)
{
  __shared__ __align__(16) unsigned short xs[128 * 64];
  __shared__ __align__(16) unsigned short ws[128 * 64];

  int tid = threadIdx.x;

  // ---- carry path: materialize next weight matrix ----
  if ((int)blockIdx.x >= Ggemm) {
    if (total8_2 > 0) {
      float* tb = (float*)xs;
      if (tid < 16) tb[tid] = NF4C[tid];
      __syncthreads();
      int nblk2 = gridDim.x - Ggemm;
      const int KB2 = K2 >> 6;
      for (long i = (long)((int)blockIdx.x - Ggemm) * 256 + tid; i < total8_2;
           i += (long)nblk2 * 256) {
        long e = i << 3;
        int rd = (int)(e / K2), k = (int)(e - (long)rd * K2);
        int srcn = ilv2 ? ((rd & 1) * F_FFN + (rd >> 1)) : rd;
        float am = AM2[(size_t)srcn * KB2 + (k >> 6)];
        const int4* cp = (const int4*)(C2 + (size_t)srcn * K2 + k);
        int4 a = cp[0], b = cp[1];
        uint4 o;
        o.x = (unsigned)f2b(tb[a.x] * am) | ((unsigned)f2b(tb[a.y] * am) << 16);
        o.y = (unsigned)f2b(tb[a.z] * am) | ((unsigned)f2b(tb[a.w] * am) << 16);
        o.z = (unsigned)f2b(tb[b.x] * am) | ((unsigned)f2b(tb[b.y] * am) << 16);
        o.w = (unsigned)f2b(tb[b.z] * am) | ((unsigned)f2b(tb[b.w] * am) << 16);
        *(uint4*)(W2 + e) = o;
      }
    }
    return;
  }

  // XCD-chunked bijective swizzle over the GEMM sub-grid
  int nwg = Ggemm;
  int q8 = nwg >> 3, r8 = nwg & 7;
  int xcd = blockIdx.x & 7, pos = blockIdx.x >> 3;
  int wgid = (xcd < r8) ? (xcd * (q8 + 1) + pos)
                        : (r8 * (q8 + 1) + (xcd - r8) * q8 + pos);
  int nb = N >> 7;
  int per = mb * nb;
  int slice = wgid / per; int rem = wgid - slice * per;
  int nblk = rem / mb, mblk = rem - nblk * mb;
  int row0 = mblk << 7, col0 = nblk << 7;
  int KBtot = K >> 6, kcnt = KBtot / splitk, kbeg = slice * kcnt;

  int wave = tid >> 6, lane = tid & 63;
  int fr = lane & 15, fg = lane >> 4, s7 = fr & 7;
  int wm = (wave >> 1) * 64, wn = (wave & 1) * 64;
  int xg = lane >> 3;
  int xcol = (((lane & 7) ^ (xg & 7)) << 3);

  const unsigned short* Xbase = X + (size_t)row0 * K + (size_t)kbeg * 64;
  const unsigned short* Wbase = W + (size_t)col0 * K + (size_t)kbeg * 64;

  f32x4 accm[4][4];
  #pragma unroll
  for (int i = 0; i < 4; ++i)
    #pragma unroll
    for (int j = 0; j < 4; ++j) accm[i][j] = (f32x4){0.f, 0.f, 0.f, 0.f};

  auto stage = [&](int t) {
    const unsigned short* xb = Xbase + (size_t)t * 64;
    const unsigned short* wb = Wbase + (size_t)t * 64;
    #pragma unroll
    for (int p2 = 0; p2 < 4; ++p2) {
      int c = wave * 4 + p2;
      const unsigned short* gp = xb + (size_t)(c * 8 + xg) * K + xcol;
      __builtin_amdgcn_global_load_lds(
          (const __attribute__((address_space(1))) unsigned int*)gp,
          (__attribute__((address_space(3))) unsigned int*)(xs + c * 512),
          16, 0, 0);
    }
    #pragma unroll
    for (int p2 = 0; p2 < 4; ++p2) {
      int c = wave * 4 + p2;
      const unsigned short* gp = wb + (size_t)(c * 8 + xg) * K + xcol;
      __builtin_amdgcn_global_load_lds(
          (const __attribute__((address_space(1))) unsigned int*)gp,
          (__attribute__((address_space(3))) unsigned int*)(ws + c * 512),
          16, 0, 0);
    }
  };
  auto compute = [&]() {
    bf16x8 b0[4], b1[4];
    #pragma unroll
    for (int ni = 0; ni < 4; ++ni) {
      const unsigned short* wr = ws + (wn + ni * 16 + fr) * 64;
      b0[ni] = *(const bf16x8*)(wr + ((fg ^ s7) << 3));
      b1[ni] = *(const bf16x8*)(wr + (((4 | fg) ^ s7) << 3));
    }
    #pragma unroll
    for (int mi = 0; mi < 4; ++mi) {
      const unsigned short* xr = xs + (wm + mi * 16 + fr) * 64;
      bf16x8 a0 = *(const bf16x8*)(xr + ((fg ^ s7) << 3));
      bf16x8 a1 = *(const bf16x8*)(xr + (((4 | fg) ^ s7) << 3));
      #pragma unroll
      for (int ni = 0; ni < 4; ++ni) {
        accm[mi][ni] = __builtin_amdgcn_mfma_f32_16x16x32_bf16(
            a0, b0[ni], accm[mi][ni], 0, 0, 0);
        accm[mi][ni] = __builtin_amdgcn_mfma_f32_16x16x32_bf16(
            a1, b1[ni], accm[mi][ni], 0, 0, 0);
      }
    }
  };

  stage(0);
  for (int t = 0; t < kcnt; ++t) {
    __syncthreads();
    compute();
    if (t + 1 < kcnt) {
      __syncthreads();
      stage(t + 1);
    }
  }

  if (gum) {
    // ---- GUMODE epilogue: cols interleaved gate/up; out = silu(g)*u ----
    float* Tt = (float*)&xs[0];   // 128 x 32
    float* Bt = (float*)&ws[0];   // 128 x 16 (interleaved rows)
    __syncthreads();
    for (int idx = tid; idx < 128 * 32; idx += 256) {
      int rr = idx >> 5, c = idx & 31;
      int gm = row0 + rr;
      Tt[idx] = (gm < M_TOK) ? T[(size_t)gm * 32 + c] : 0.f;
    }
    for (int idx = tid; idx < 128 * 16; idx += 256) {
      int rr = idx >> 4, c = idx & 15;
      int type = rr & 1, nrow = (col0 + rr) >> 1;
      Bt[idx] = Bm[((size_t)type * F_FFN + nrow) * LRANK + c];
    }
    __syncthreads();
    #pragma unroll
    for (int mi = 0; mi < 4; ++mi)
      #pragma unroll
      for (int ni = 0; ni < 4; ++ni) {
        int gm0 = row0 + wm + mi * 16 + fg * 4;
        int gnl = wn + ni * 16 + fr;
        #pragma unroll
        for (int r = 0; r < 4; ++r) {
          int gm = gm0 + r;
          float vv = accm[mi][ni][r];
          const float* tr = Tt + (wm + mi * 16 + fg * 4 + r) * 32 + ((gnl & 1) << 4);
          const float* br = Bt + gnl * 16;
          float s = 0.f;
          #pragma unroll
          for (int c = 0; c < 16; ++c) s += tr[c] * br[c];
          vv += 2.0f * s;
          float prt = __shfl_xor(vv, 1);
          if (gm < M_TOK && !(fr & 1)) {
            float sig = 1.0f / (1.0f + expf(-vv));
            GB[(size_t)gm * F_FFN + ((col0 + gnl) >> 1)] = f2b(vv * sig * prt);
          }
        }
      }
    return;
  }

  // optional fused LoRA-2: stage T[128][16], Bm[128][16] into (free) LDS
  float* Tt = (float*)&xs[0];
  float* Bt = (float*)&ws[0];
  if (T) {
    __syncthreads();
    int toff = (col0 >> sh) << 4;
    for (int idx = tid; idx < 128 * 16; idx += 256) {
      int rr = idx >> 4, c = idx & 15;
      int gm = row0 + rr;
      Tt[idx] = (gm < M_TOK) ? T[(size_t)gm * nr + toff + c] : 0.f;
      Bt[idx] = Bm[(size_t)(col0 + rr) * LRANK + c];
    }
    __syncthreads();
  }

  #pragma unroll
  for (int mi = 0; mi < 4; ++mi)
    #pragma unroll
    for (int ni = 0; ni < 4; ++ni) {
      int gm0 = row0 + wm + mi * 16 + fg * 4;
      int gnl = wn + ni * 16 + fr;
      int gn = col0 + gnl;
      #pragma unroll
      for (int r = 0; r < 4; ++r) {
        int gm = gm0 + r;
        if (gm < M_TOK) {
          size_t idx = (size_t)gm * N + gn;
          float vv = accm[mi][ni][r];
          if (T) {
            const float* tr = Tt + (wm + mi * 16 + fg * 4 + r) * 16;
            const float* br = Bt + gnl * 16;
            float s = 0.f;
            #pragma unroll
            for (int c = 0; c < 16; ++c) s += tr[c] * br[c];
            vv += 2.0f * s;
          }
          if (splitk > 1)       atomicAdd(&O[idx], vv);
          else if (acc_mode)    O[idx] += vv;
          else                  O[idx] = vv;
        }
      }
    }
}

// ---------------------------------------------------------------------------
// LoRA stage 1, 4 m-rows per block: T[m][bi*16+g] = sum_k X[m][k]*A[bi][g][k]
__global__ __launch_bounds__(256) void lora1(
    const unsigned short* __restrict__ X, const float* __restrict__ A,
    float* __restrict__ T, int K)
{
  int m0 = blockIdx.x * 4, bi = blockIdx.y, nmat = gridDim.y;
  int g = threadIdx.x >> 4, l16 = threadIdx.x & 15;
  const float* ar = A + (size_t)bi * LRANK * K + (size_t)g * K;
  const unsigned short* x0 = X + (size_t)m0 * K;
  float s0 = 0.f, s1 = 0.f, s2 = 0.f, s3 = 0.f;
  for (int kk = l16 * 4; kk < K; kk += 64) {
    float4 av = *(const float4*)(ar + kk);
    ushort4 v0 = *(const ushort4*)(x0 + kk);
    ushort4 v1 = *(const ushort4*)(x0 + K + kk);
    ushort4 v2 = *(const ushort4*)(x0 + 2 * K + kk);
    ushort4 v3 = *(const ushort4*)(x0 + 3 * K + kk);
    s0 += b2f(v0.x)*av.x + b2f(v0.y)*av.y + b2f(v0.z)*av.z + b2f(v0.w)*av.w;
    s1 += b2f(v1.x)*av.x + b2f(v1.y)*av.y + b2f(v1.z)*av.z + b2f(v1.w)*av.w;
    s2 += b2f(v2.x)*av.x + b2f(v2.y)*av.y + b2f(v2.z)*av.z + b2f(v2.w)*av.w;
    s3 += b2f(v3.x)*av.x + b2f(v3.y)*av.y + b2f(v3.z)*av.z + b2f(v3.w)*av.w;
  }
  #pragma unroll
  for (int off = 8; off; off >>= 1) {
    s0 += __shfl_down(s0, off, 16);
    s1 += __shfl_down(s1, off, 16);
    s2 += __shfl_down(s2, off, 16);
    s3 += __shfl_down(s3, off, 16);
  }
  if (l16 == 0) {
    size_t base = ((size_t)m0 * nmat + bi) * LRANK + g;
    size_t rs = (size_t)nmat * LRANK;
    T[base] = s0; T[base + rs] = s1; T[base + 2*rs] = s2; T[base + 3*rs] = s3;
  }
}

// LoRA stage 2 (separate path for split-K GEMMs), 8 m-rows per block
__global__ __launch_bounds__(256) void lora2(
    float* __restrict__ O, const float* __restrict__ T,
    const float* __restrict__ Bm, int N, int sh, int nr)
{
  int m0 = blockIdx.y * 8;
  int n = blockIdx.x * 256 + threadIdx.x;
  __shared__ float ts[8 * 48];
  for (int i = threadIdx.x; i < 8 * nr; i += 256)
    ts[(i / nr) * 48 + (i % nr)] = T[(size_t)(m0 + i / nr) * nr + (i % nr)];
  __syncthreads();
  const float4* br = (const float4*)(Bm + (size_t)n * LRANK);
  float4 b0 = br[0], b1 = br[1], b2 = br[2], b3 = br[3];
  int toff = ((n >> sh) << 4);
  #pragma unroll
  for (int mi = 0; mi < 8; ++mi) {
    const float* tsb = ts + mi * 48 + toff;
    float s = b0.x*tsb[0] + b0.y*tsb[1] + b0.z*tsb[2] + b0.w*tsb[3]
            + b1.x*tsb[4] + b1.y*tsb[5] + b1.z*tsb[6] + b1.w*tsb[7]
            + b2.x*tsb[8] + b2.y*tsb[9] + b2.z*tsb[10] + b2.w*tsb[11]
            + b3.x*tsb[12] + b3.y*tsb[13] + b3.z*tsb[14] + b3.w*tsb[15];
    O[(size_t)(m0 + mi) * N + n] += 2.0f * s;
  }
}

// ---------------------------------------------------------------------------
__global__ __launch_bounds__(256) void rmsnorm_k(
    const float* __restrict__ H, const float* __restrict__ W,
    unsigned short* __restrict__ X, int D)
{
  int m = blockIdx.x;
  const float* hr = H + (size_t)m * D;
  float s = 0.f;
  for (int i = threadIdx.x; i < D; i += 256) { float v = hr[i]; s += v * v; }
  __shared__ float red[4];
  #pragma unroll
  for (int off = 32; off; off >>= 1) s += __shfl_down(s, off, 64);
  if ((threadIdx.x & 63) == 0) red[threadIdx.x >> 6] = s;
  __syncthreads();
  float tot = red[0] + red[1] + red[2] + red[3];
  float inv = rsqrtf(tot / (float)D + 1e-6f);
  for (int i = threadIdx.x; i < D; i += 256)
    X[(size_t)m * D + i] = f2b(hr[i] * inv * W[i]);
}

__global__ void rope_table(float* __restrict__ cosT, float* __restrict__ sinT)
{
  int idx = blockIdx.x * 64 + threadIdx.x;
  if (idx >= SEQ * 64) return;
  int s = idx >> 6, j = idx & 63;
  float inv = powf(10000.0f, -(float)(2 * j) / 128.0f);
  float f = (float)s * inv;
  cosT[idx] = cosf(f);
  sinT[idx] = sinf(f);
}

// ---------------------------------------------------------------------------
// Attention with fused RoPE: grid (B*H, 5 row-tiles of 16). Roped K and
// roped Q tile staged in LDS (pad 132), wave-parallel softmax, PV from L2.
// ---------------------------------------------------------------------------
__global__ __launch_bounds__(256) void attn_k(
    const float* __restrict__ QKV, const int* __restrict__ amask,
    const float* __restrict__ cosT, const float* __restrict__ sinT,
    unsigned short* __restrict__ O)
{
  int bh = blockIdx.x, it = blockIdx.y;
  int b = bh >> 4, h = bh & (NHEAD - 1);
  const int STR = 3 * D_MODEL;
  __shared__ float ks[SEQ * 132];
  __shared__ float qs[ATILE * 132];
  __shared__ float sc[ATILE * 80];
  __shared__ int am[SEQ];
  const float scale = 0.08838834764831845f;  // 1/sqrt(128)

  const float* Kb = QKV + (size_t)(b * SEQ) * STR + D_MODEL + h * 128;
  for (int idx = threadIdx.x; idx < SEQ * 16; idx += 256) {
    int j = idx >> 4, dq = (idx & 15) << 2;
    float4 a = *(const float4*)(Kb + (size_t)j * STR + dq);
    float4 bb = *(const float4*)(Kb + (size_t)j * STR + dq + 64);
    float4 c4 = *(const float4*)(cosT + j * 64 + dq);
    float4 s4 = *(const float4*)(sinT + j * 64 + dq);
    float* kr = ks + j * 132 + dq;
    kr[0] = a.x*c4.x - bb.x*s4.x; kr[1] = a.y*c4.y - bb.y*s4.y;
    kr[2] = a.z*c4.z - bb.z*s4.z; kr[3] = a.w*c4.w - bb.w*s4.w;
    kr[64] = bb.x*c4.x + a.x*s4.x; kr[65] = bb.y*c4.y + a.y*s4.y;
    kr[66] = bb.z*c4.z + a.z*s4.z; kr[67] = bb.w*c4.w + a.w*s4.w;
  }
  const float* Qb = QKV + (size_t)(b * SEQ) * STR + h * 128;
  for (int idx = threadIdx.x; idx < ATILE * 16; idx += 256) {
    int il = idx >> 4, dq = (idx & 15) << 2;
    int i = it * ATILE + il;
    if (i < SEQ) {
      float4 a = *(const float4*)(Qb + (size_t)i * STR + dq);
      float4 bb = *(const float4*)(Qb + (size_t)i * STR + dq + 64);
      float4 c4 = *(const float4*)(cosT + i * 64 + dq);
      float4 s4 = *(const float4*)(sinT + i * 64 + dq);
      float* qr = qs + il * 132 + dq;
      qr[0] = a.x*c4.x - bb.x*s4.x; qr[1] = a.y*c4.y - bb.y*s4.y;
      qr[2] = a.z*c4.z - bb.z*s4.z; qr[3] = a.w*c4.w - bb.w*s4.w;
      qr[64] = bb.x*c4.x + a.x*s4.x; qr[65] = bb.y*c4.y + a.y*s4.y;
      qr[66] = bb.z*c4.z + a.z*s4.z; qr[67] = bb.w*c4.w + a.w*s4.w;
    }
  }
  for (int j = threadIdx.x; j < SEQ; j += 256) am[j] = amask[b * SEQ + j];
  __syncthreads();

  int wave = threadIdx.x >> 6, lane = threadIdx.x & 63;
  #pragma unroll
  for (int r = 0; r < 4; ++r) {
    int il = wave * 4 + r;
    int i = it * ATILE + il;
    if (i < SEQ) {
      const float4* qr = (const float4*)(qs + il * 132);
      int j1 = lane, j2 = lane + 64;
      float v1 = -1e9f, v2 = -1e9f;
      if (j1 <= i && am[j1]) {
        const float4* kr = (const float4*)(ks + j1 * 132);
        float s = 0.f;
        #pragma unroll 8
        for (int d = 0; d < 32; ++d) {
          float4 a = qr[d], c = kr[d];
          s += a.x*c.x + a.y*c.y + a.z*c.z + a.w*c.w;
        }
        v1 = s * scale;
      }
      if (j2 < SEQ && j2 <= i && am[j2]) {
        const float4* kr = (const float4*)(ks + j2 * 132);
        float s = 0.f;
        #pragma unroll 8
        for (int d = 0; d < 32; ++d) {
          float4 a = qr[d], c = kr[d];
          s += a.x*c.x + a.y*c.y + a.z*c.z + a.w*c.w;
        }
        v2 = s * scale;
      }
      float mx = fmaxf(v1, v2);
      #pragma unroll
      for (int off = 32; off; off >>= 1) mx = fmaxf(mx, __shfl_xor(mx, off));
      float e1 = __expf(v1 - mx);
      float e2 = (j2 < SEQ) ? __expf(v2 - mx) : 0.f;
      float sum = e1 + e2;
      #pragma unroll
      for (int off = 32; off; off >>= 1) sum += __shfl_xor(sum, off);
      float inv = 1.0f / sum;
      sc[il * 80 + j1] = e1 * inv;
      if (j2 < SEQ) sc[il * 80 + j2] = e2 * inv;
    }
  }
  __syncthreads();

  const float* Vbase = QKV + (size_t)(b * SEQ) * STR + 2 * D_MODEL + h * 128;
  for (int idx = threadIdx.x; idx < ATILE * 32; idx += 256) {
    int il = idx >> 5, d4 = (idx & 31) << 2;
    int i = it * ATILE + il;
    if (i >= SEQ) continue;
    float4 acc = {0.f, 0.f, 0.f, 0.f};
    const float* sr = sc + il * 80;
    for (int j = 0; j < SEQ; ++j) {
      float pp = sr[j];
      float4 v = *(const float4*)(Vbase + (size_t)j * STR + d4);
      acc.x += pp * v.x; acc.y += pp * v.y; acc.z += pp * v.z; acc.w += pp * v.w;
    }
    unsigned short* op = O + (size_t)(b * SEQ + i) * D_MODEL + h * 128 + d4;
    op[0] = f2b(acc.x); op[1] = f2b(acc.y); op[2] = f2b(acc.z); op[3] = f2b(acc.w);
  }
}

__global__ void embed_gather(const float* __restrict__ E, const int* __restrict__ ids,
                             float* __restrict__ H)
{
  size_t idx = (size_t)blockIdx.x * 256 + threadIdx.x;
  int m = (int)(idx / D_MODEL);
  int n = (int)(idx % D_MODEL);
  H[idx] = E[(size_t)ids[m] * D_MODEL + n];
}

__global__ __launch_bounds__(256) void final_k(
    const float* __restrict__ H, const int* __restrict__ amask,
    const float* __restrict__ W, float* __restrict__ out)
{
  int b = blockIdx.x;
  __shared__ int len;
  if (threadIdx.x == 0) {
    int s = 0;
    for (int j = 0; j < SEQ; ++j) s += amask[b * SEQ + j];
    len = s - 1;
  }
  __syncthreads();
  const float* hr = H + ((size_t)(b * SEQ + len) * D_MODEL);
  float s = 0.f;
  for (int i = threadIdx.x; i < D_MODEL; i += 256) { float v = hr[i]; s += v * v; }
  __shared__ float red[4];
  #pragma unroll
  for (int off = 32; off; off >>= 1) s += __shfl_down(s, off, 64);
  if ((threadIdx.x & 63) == 0) red[threadIdx.x >> 6] = s;
  __syncthreads();
  float tot = red[0] + red[1] + red[2] + red[3];
  float inv = rsqrtf(tot / (float)D_MODEL + 1e-6f);
  for (int i = threadIdx.x; i < D_MODEL; i += 256)
    out[(size_t)b * D_MODEL + i] = hr[i] * inv * W[i];
}

// ---------------------------------------------------------------------------
extern "C" void kernel_launch(void* const* d_in, const int* in_sizes, int n_in,
                              void* d_out, int out_size, void* d_ws, size_t ws_size,
                              hipStream_t stream) {
  const int*   ids     = (const int*)d_in[0];
  const int*   amask   = (const int*)d_in[1];
  const float* embed   = (const float*)d_in[2];
  const float* ln_attn = (const float*)d_in[3];
  const float* ln_mlp  = (const float*)d_in[4];
  const float* ln_fin  = (const float*)d_in[5];
  const int*   qkvC    = (const int*)d_in[6];
  const float* qkvS    = (const float*)d_in[7];
  const float* qkvA    = (const float*)d_in[8];
  const float* qkvB    = (const float*)d_in[9];
  const int*   oC      = (const int*)d_in[10];
  const float* oS      = (const float*)d_in[11];
  const float* oA      = (const float*)d_in[12];
  const float* oB      = (const float*)d_in[13];
  const int*   guC     = (const int*)d_in[14];
  const float* guS     = (const float*)d_in[15];
  const float* guA     = (const float*)d_in[16];
  const float* guB     = (const float*)d_in[17];
  const int*   dnC     = (const int*)d_in[18];
  const float* dnS     = (const float*)d_in[19];
  const float* dnA     = (const float*)d_in[20];
  const float* dnB     = (const float*)d_in[21];
  float* out = (float*)d_out;

  const int M = M_TOK, Mp = M_PAD, D = D_MODEL, F = F_FFN, R = LRANK;
  float* p = (float*)d_ws;
  float* h    = p; p += (size_t)Mp * D;
  float* qkv  = p; p += (size_t)Mp * 3 * D;
  float* t    = p; p += (size_t)Mp * 48;
  float* cosT = p; p += SEQ * 64;
  float* sinT = p; p += SEQ * 64;
  unsigned short* xbf = (unsigned short*)p; p += (size_t)Mp * D / 2;
  unsigned short* gbf = (unsigned short*)p; p += (size_t)Mp * F / 2;
  unsigned short* wQ = (unsigned short*)p; p += (size_t)3 * D * D / 2;  // 25.2 MB
  unsigned short* wO = (unsigned short*)p; p += (size_t)D * D / 2;      //  8.4 MB
  unsigned short* wG = (unsigned short*)p; p += (size_t)2 * F * D / 2;  // 67.1 MB
  unsigned short* wD = (unsigned short*)p; p += (size_t)D * F / 2;      // 33.6 MB

  rope_table<<<(SEQ*64 + 63)/64, 64, 0, stream>>>(cosT, sinT);
  embed_gather<<<(M * D)/256, 256, 0, stream>>>(embed, ids, h);
  mat_w<<<2048, 256, 0, stream>>>(qkvC, qkvS, wQ, D, (long)3*D*D/8, 0);  // layer 0 qkv

  const int mb = Mp / 128;
  const int Gqkv = mb * (3*D/128);        // 480
  const int Go   = mb * (D/128) * 4;      // 640, splitk 4
  const int Ggu  = mb * (2*F/128);        // 1280
  const int Gdn  = mb * (D/128) * 8;      // 1280, splitk 8

  for (int l = 0; l < NLAYER; ++l) {
    // ---- attention ----
    rmsnorm_k<<<M, 256, 0, stream>>>(h, ln_attn + (size_t)l * D, xbf, D);
    lora1<<<dim3(M/4, 3), 256, 0, stream>>>(xbf, qkvA + (size_t)l*3*R*D, t, D);
    // qkv GEMM (+fused LoRA) carrying mat_w(o)
    gemm_bf<<<Gqkv + MWB, 256, 0, stream>>>(
        xbf, wQ, qkv, mb, 3*D, D, 0, 1,
        t, qkvB + (size_t)l*3*D*R, 11, 48, 0, nullptr,
        oC + (size_t)l*D*D, oS + (size_t)l*D*(D/64), wO, D, (long)D*D/8, 0, Gqkv);
    attn_k<<<dim3(BATCH*NHEAD, (SEQ + ATILE - 1)/ATILE), 256, 0, stream>>>(
        qkv, amask, cosT, sinT, xbf);
    // o GEMM (split-K 4) carrying mat_w(gu, interleaved)
    gemm_bf<<<Go + MWB, 256, 0, stream>>>(
        xbf, wO, h, mb, D, D, 1, 4, nullptr, nullptr, 0, 0, 0, nullptr,
        guC + (size_t)l*2*F*D, guS + (size_t)l*2*F*(D/64), wG, D, (long)2*F*D/8, 1, Go);
    lora1<<<dim3(M/4, 1), 256, 0, stream>>>(xbf, oA + (size_t)l*R*D, t, D);
    lora2<<<dim3(D/256, M/8), 256, 0, stream>>>(h, t, oB + (size_t)l*D*R, D, 11, 16);

    // ---- MLP ----
    rmsnorm_k<<<M, 256, 0, stream>>>(h, ln_mlp + (size_t)l * D, xbf, D);
    lora1<<<dim3(M/4, 2), 256, 0, stream>>>(xbf, guA + (size_t)l*2*R*D, t, D);
    // gu GEMM (GUMODE) carrying mat_w(down)
    gemm_bf<<<Ggu + MWB, 256, 0, stream>>>(
        xbf, wG, nullptr, mb, 2*F, D, 0, 1,
        t, guB + (size_t)l*2*F*R, 0, 32, 1, gbf,
        dnC + (size_t)l*D*F, dnS + (size_t)l*D*(F/64), wD, F, (long)D*F/8, 0, Ggu);
    // down GEMM (split-K 8) carrying mat_w(qkv, next layer)
    if (l + 1 < NLAYER) {
      gemm_bf<<<Gdn + MWB, 256, 0, stream>>>(
          gbf, wD, h, mb, D, F, 1, 8, nullptr, nullptr, 0, 0, 0, nullptr,
          qkvC + (size_t)(l+1)*3*D*D, qkvS + (size_t)(l+1)*3*D*(D/64),
          wQ, D, (long)3*D*D/8, 0, Gdn);
    } else {
      gemm_bf<<<Gdn, 256, 0, stream>>>(
          gbf, wD, h, mb, D, F, 1, 8, nullptr, nullptr, 0, 0, 0, nullptr,
          nullptr, nullptr, nullptr, D, 0, 0, Gdn);
    }
    lora1<<<dim3(M/4, 1), 256, 0, stream>>>(gbf, dnA + (size_t)l*R*F, t, F);
    lora2<<<dim3(D/256, M/8), 256, 0, stream>>>(h, t, dnB + (size_t)l*D*R, D, 11, 16);
  }
  final_k<<<BATCH, 256, 0, stream>>>(h, amask, ln_fin, out);
}